// Round 5
// baseline (743.843 us; speedup 1.0000x reference)
//
#include <hip/hip_runtime.h>
#include <hip/hip_bf16.h>

#define DEVI __device__ __forceinline__

typedef short bf16x8 __attribute__((ext_vector_type(8)));
typedef float f32x4  __attribute__((ext_vector_type(4)));

static constexpr int Bb   = 128;
static constexpr int Ss   = 512;
static constexpr int Hh   = 1024;
static constexpr int Ee   = 512;
static constexpr int Vv   = 50257;
static constexpr int TWOH = 2048;

DEVI short f2bf(float f){ __hip_bfloat16 h = __float2bfloat16(f); return *reinterpret_cast<short*>(&h); }
DEVI float bf2f(short s){ __hip_bfloat16 h = *reinterpret_cast<__hip_bfloat16*>(&s); return __bfloat162float(h); }

DEVI bf16x8 pack8(f32x4 a, f32x4 b){
  bf16x8 v;
  v[0]=f2bf(a[0]); v[1]=f2bf(a[1]); v[2]=f2bf(a[2]); v[3]=f2bf(a[3]);
  v[4]=f2bf(b[0]); v[5]=f2bf(b[1]); v[6]=f2bf(b[2]); v[7]=f2bf(b[3]);
  return v;
}

DEVI void gld_lds16(const void* g, void* l){
  __builtin_amdgcn_global_load_lds((const __attribute__((address_space(1))) void*)g,
                                   (__attribute__((address_space(3))) void*)l, 16, 0, 0);
}

DEVI f32x4 mfma16(bf16x8 a, bf16x8 b, f32x4 c){
  return __builtin_amdgcn_mfma_f32_16x16x32_bf16(a, b, c, 0, 0, 0);
}

// ---------------- enc fp32 -> bf16, fully vectorized streaming pass ----------------
// B*S*2H = 134,217,728 elems; 65536 blocks x 256 thr x 8 elems covers it exactly.
__global__ void k_enc2bf(const float* __restrict__ enc, short* __restrict__ encb)
{
  const size_t i = ((size_t)blockIdx.x*256 + threadIdx.x) * 8;
  f32x4 f0 = *(const f32x4*)(enc + i);
  f32x4 f1 = *(const f32x4*)(enc + i + 4);
  *(bf16x8*)(encb + i) = pack8(f0, f1);
}

// ---------------- prep: convert W_ae->bf16, h->bf16, gather emb into x_bf16 ----------------
__global__ void k_prep(const float* __restrict__ wae, short* __restrict__ waeb,
                       const float* __restrict__ h, short* __restrict__ hb,
                       const int* __restrict__ dec_in, const float* __restrict__ emb,
                       short* __restrict__ xb)
{
  const int total_wae = Hh*TWOH;
  const int total_h   = Bb*Hh;
  const int total_emb = Bb*Ee;
  const int total = total_wae + total_h + total_emb;
  for (int i = blockIdx.x*blockDim.x + threadIdx.x; i < total; i += gridDim.x*blockDim.x){
    if (i < total_wae) waeb[i] = f2bf(wae[i]);
    else if (i < total_wae + total_h){ int j = i - total_wae; hb[j] = f2bf(h[j]); }
    else {
      int j = i - total_wae - total_h;
      int b = j >> 9, e = j & 511;
      xb[b*2560 + e] = f2bf(emb[(size_t)dec_in[b]*Ee + e]);
    }
  }
}

// ---------------- scores GEMM: M=65536 x N=1024 x K=2048, fused tanh-reduce ------
// 128x256 tile, 8 waves (2Mx4N), BK=64, double-buffered LDS (96KB) with
// prefetch-before-compute (T3 minimum-2-phase): next tile's global_load_lds
// issued before the MFMAs on the current buffer; ONE barrier per K-step.
// Linear block mapping keeps all XCDs in the same rt-window (L3 sharing).
template<bool BF16A>
__launch_bounds__(512)
__global__ void k_scores(const float* __restrict__ enc, const short* __restrict__ encbf,
                         const short* __restrict__ waeb,
                         const float* __restrict__ ahb, const float* __restrict__ b_ah,
                         const float* __restrict__ b_ae, const float* __restrict__ wsc,
                         float* __restrict__ scores)
{
  __shared__ __align__(16) short As[2][128*64];
  __shared__ __align__(16) short Bs[2][256*64];
  const int p  = blockIdx.x;
  const int rt = p >> 2, nb = p & 3;
  const int tid = threadIdx.x, wid = tid>>6, lane = tid&63;
  const int wr = wid>>2, wc = wid&3;
  const int srow = lane>>3, l7 = lane&7;
  const int swk = (l7 ^ srow) * 8;               // pre-swizzled k-chunk (elems)
  f32x4 acc[4][4] = {};
  const float* Af  = enc   + (size_t)rt*128*TWOH;
  const short* Ab  = encbf + (size_t)rt*128*TWOH;
  const short* Bbp = waeb  + (size_t)nb*256*TWOH;

  f32x4 pa0[2], pa1[2];                          // fp32-A fallback pending regs

  auto stageA = [&](int s, int kt){
    #pragma unroll
    for (int i=0;i<2;++i){
      int c = wid*2+i, row = c*8+srow;
      gld_lds16(Ab + (size_t)row*TWOH + kt*64 + swk, (char*)As[s] + c*1024);
    }
  };
  auto stageB = [&](int s, int kt){
    #pragma unroll
    for (int i=0;i<4;++i){
      int c = wid*4+i, row = c*8+srow;
      gld_lds16(Bbp + (size_t)row*TWOH + kt*64 + swk, (char*)Bs[s] + c*1024);
    }
  };
  auto prefA = [&](int kt){
    #pragma unroll
    for (int i=0;i<2;++i){
      int row = (wid*2+i)*8+srow;
      const float* bp = Af + (size_t)row*TWOH + kt*64 + l7*8;
      pa0[i] = *(const f32x4*)bp; pa1[i] = *(const f32x4*)(bp+4);
    }
  };
  auto commitA = [&](int s){
    #pragma unroll
    for (int i=0;i<2;++i){
      int row = (wid*2+i)*8+srow;
      *(bf16x8*)((char*)As[s] + row*128 + ((l7^srow)<<4)) = pack8(pa0[i], pa1[i]);
    }
  };

  if constexpr (BF16A) stageA(0,0);
  else { prefA(0); commitA(0); }
  stageB(0,0);
  __syncthreads();

  int cur = 0;
  for (int kt=0; kt<32; ++kt){
    if (kt<31){
      if constexpr (BF16A) stageA(cur^1, kt+1); else prefA(kt+1);
      stageB(cur^1, kt+1);
    }
    #pragma unroll
    for (int kk=0;kk<2;++kk){
      bf16x8 af[4], bq[4];
      const int sw = (kk*64 + (lane>>4)*16) ^ (l7<<4);
      #pragma unroll
      for (int i=0;i<4;++i) af[i] = *(const bf16x8*)((const char*)As[cur] + (wr*64+i*16+(lane&15))*128 + sw);
      #pragma unroll
      for (int j=0;j<4;++j) bq[j] = *(const bf16x8*)((const char*)Bs[cur] + (wc*64+j*16+(lane&15))*128 + sw);
      #pragma unroll
      for (int i=0;i<4;++i)
        #pragma unroll
        for (int j=0;j<4;++j)
          acc[i][j] = mfma16(af[i], bq[j], acc[i][j]);
    }
    if constexpr (!BF16A){ if (kt<31) commitA(cur^1); }
    __syncthreads();
    cur ^= 1;
  }
  // epilogue: scores[m] += sum_n tanh(ah[b,n]+b_ah+b_ae+ae)*w_score[n]
  const int lo = lane&15, hi = lane>>4;
  const int b = rt>>2;
  float w4[4], t4[4];
  #pragma unroll
  for (int j=0;j<4;++j){
    int n = nb*256 + wc*64 + j*16 + lo;
    w4[j] = wsc[n];
    t4[j] = ahb[b*Hh + n] + b_ah[n] + b_ae[n];
  }
  #pragma unroll
  for (int i=0;i<4;++i){
    #pragma unroll
    for (int q2=0;q2<4;++q2){
      int m = rt*128 + wr*64 + i*16 + hi*4 + q2;
      float s = 0.f;
      #pragma unroll
      for (int j=0;j<4;++j) s += tanhf(t4[j] + acc[i][j][q2]) * w4[j];
      s += __shfl_xor(s,1); s += __shfl_xor(s,2); s += __shfl_xor(s,4); s += __shfl_xor(s,8);
      if (lo == 0) atomicAdd(&scores[m], s);
    }
  }
}

// ---------------- generic 128-row GEMM: A[128,K] bf16 ws, B[N,K] fp32 global --------------
// Double-buffered: A prefetched via gld_lds into buf^1; B via T14 reg-split
// (global fp32 loads issued before compute, packed+ds_written after MFMAs).
template<int MODE>
__launch_bounds__(256)
__global__ void k_gemm128(const short* __restrict__ A, int lda,
                          const float* __restrict__ B0, const float* __restrict__ B1,
                          float* __restrict__ O0, float* __restrict__ O1,
                          const float* __restrict__ bias, int kiters)
{
  __shared__ __align__(16) short As[2][128*64];
  __shared__ __align__(16) short Bs[2][128*64];
  const int nb = blockIdx.x;
  const int tid = threadIdx.x, wid = tid>>6, lane = tid&63;
  const int wr = wid>>1, wc = wid&1;
  const int srow = lane>>3, l7 = lane&7;
  const int swk = (l7 ^ srow) * 8;

  const float* Bt; int noff; float* Ot; int ostride;
  if constexpr (MODE==0){
    if (nb < 8){ Bt = B0; noff = 0;    Ot = O0; ostride = Hh;   }
    else       { Bt = B1; noff = 1024; Ot = O1; ostride = 3*Hh; }
  } else if constexpr (MODE==1){ Bt = B0; noff = 0; Ot = O0; ostride = 3*Hh; }
  else { Bt = B0; noff = 0; Ot = O0; ostride = Vv; }

  f32x4 acc[4][4] = {};
  f32x4 pb0[4], pb1[4];

  auto stageA = [&](int s, int kt){
    #pragma unroll
    for (int i=0;i<4;++i){
      int c = wid*4+i, row = c*8+srow;
      gld_lds16(A + (size_t)row*lda + kt*64 + swk, (char*)As[s] + c*1024);
    }
  };
  auto prefB = [&](int kt){
    #pragma unroll
    for (int i=0;i<4;++i){
      int row = (wid*4+i)*8+srow;
      int n = nb*128 + row - noff;
      if constexpr (MODE==2) n = (n > Vv-1) ? (Vv-1) : n;
      const float* bp = Bt + (size_t)n*lda + kt*64 + l7*8;
      pb0[i] = *(const f32x4*)bp; pb1[i] = *(const f32x4*)(bp+4);
    }
  };
  auto commitB = [&](int s){
    #pragma unroll
    for (int i=0;i<4;++i){
      int row = (wid*4+i)*8+srow;
      *(bf16x8*)((char*)Bs[s] + row*128 + ((l7^srow)<<4)) = pack8(pb0[i], pb1[i]);
    }
  };

  const int kt0 = blockIdx.y * kiters, kend = kt0 + kiters;
  stageA(0, kt0); prefB(kt0); commitB(0);
  __syncthreads();

  int cur = 0;
  for (int kt = kt0; kt < kend; ++kt){
    if (kt+1 < kend){ stageA(cur^1, kt+1); prefB(kt+1); }
    #pragma unroll
    for (int kk=0;kk<2;++kk){
      bf16x8 af[4], bq[4];
      const int sw = (kk*64 + (lane>>4)*16) ^ (l7<<4);
      #pragma unroll
      for (int i=0;i<4;++i) af[i] = *(const bf16x8*)((const char*)As[cur] + (wr*64+i*16+(lane&15))*128 + sw);
      #pragma unroll
      for (int j=0;j<4;++j) bq[j] = *(const bf16x8*)((const char*)Bs[cur] + (wc*64+j*16+(lane&15))*128 + sw);
      #pragma unroll
      for (int i=0;i<4;++i)
        #pragma unroll
        for (int j=0;j<4;++j)
          acc[i][j] = mfma16(af[i], bq[j], acc[i][j]);
    }
    if (kt+1 < kend) commitB(cur^1);
    __syncthreads();
    cur ^= 1;
  }
  const int lo = lane&15, hi = lane>>4;
  #pragma unroll
  for (int i=0;i<4;++i){
    #pragma unroll
    for (int j=0;j<4;++j){
      int n = nb*128 + wc*64 + j*16 + lo - noff;
      #pragma unroll
      for (int q=0;q<4;++q){
        int m = wr*64 + i*16 + hi*4 + q;
        float v = acc[i][j][q];
        if constexpr (MODE==2){
          if (n < Vv) O0[(size_t)m*Vv + n] = v + bias[n];
        } else {
          atomicAdd(&Ot[(size_t)m*ostride + n], v);
        }
      }
    }
  }
}

// ---------------- softmax over S=512 per batch row ----------------
__global__ void k_softmax(const float* __restrict__ scores, float* __restrict__ attn)
{
  __shared__ float red[512];
  const int b = blockIdx.x, tid = threadIdx.x;
  float v = scores[b*Ss + tid];
  red[tid] = v; __syncthreads();
  for (int off=256; off>0; off>>=1){ if (tid<off) red[tid] = fmaxf(red[tid], red[tid+off]); __syncthreads(); }
  float mx = red[0]; __syncthreads();
  float e = __expf(v - mx);
  red[tid] = e; __syncthreads();
  for (int off=256; off>0; off>>=1){ if (tid<off) red[tid] += red[tid+off]; __syncthreads(); }
  attn[b*Ss + tid] = e / red[0];
}

// ---------------- ctx partial: bf16 enc, 4 row-chunks of 128, vectorized ----------------
__global__ void k_ctx_bf16(const short* __restrict__ encb, const float* __restrict__ attn,
                           float* __restrict__ ctxp)
{
  __shared__ float a[128];
  const int bid = blockIdx.x, b = bid>>2, ch = bid&3, tid = threadIdx.x;
  if (tid < 128) a[tid] = attn[b*Ss + ch*128 + tid];
  __syncthreads();
  const short* e0 = encb + (size_t)(b*Ss + ch*128)*TWOH + tid*8;
  float s[8] = {};
  for (int r=0; r<128; ++r){
    bf16x8 v = *(const bf16x8*)(e0 + (size_t)r*TWOH);
    float w = a[r];
    #pragma unroll
    for (int j=0;j<8;++j) s[j] += w * bf2f(v[j]);
  }
  float* o = ctxp + (size_t)ch*Bb*TWOH + (size_t)b*TWOH + tid*8;
  #pragma unroll
  for (int j=0;j<8;++j) o[j] = s[j];
}

__global__ void k_ctxfin(const float* __restrict__ ctxp, short* __restrict__ xb)
{
  const int g = blockIdx.x*256 + threadIdx.x;
  const int b = g >> 11, col = g & 2047;
  const int N = Bb*TWOH;
  float v = ctxp[g] + ctxp[N+g] + ctxp[2*N+g] + ctxp[3*N+g];
  xb[b*2560 + 512 + col] = f2bf(v);
}

// fallback (small ws): fp32 enc, writes xb directly
__global__ void k_ctx_f32(const float* __restrict__ enc, const float* __restrict__ attn,
                          short* __restrict__ xb)
{
  __shared__ float a[512];
  const int ch = blockIdx.x, b = blockIdx.y, tid = threadIdx.x;
  a[tid]     = attn[b*Ss + tid];
  a[tid+256] = attn[b*Ss + tid + 256];
  __syncthreads();
  const float* e0 = enc + (size_t)b*Ss*TWOH + ch*256 + tid;
  float s0=0.f, s1=0.f, s2=0.f, s3=0.f;
  for (int s=0; s<512; s+=4){
    s0 += a[s]   * e0[(size_t)(s  )*TWOH];
    s1 += a[s+1] * e0[(size_t)(s+1)*TWOH];
    s2 += a[s+2] * e0[(size_t)(s+2)*TWOH];
    s3 += a[s+3] * e0[(size_t)(s+3)*TWOH];
  }
  xb[b*2560 + 512 + ch*256 + tid] = f2bf(s0+s1+s2+s3);
}

// ---------------- GRU gates + h_new ----------------
__global__ void k_gates(const float* __restrict__ gx, const float* __restrict__ gh,
                        const float* __restrict__ b_ih, const float* __restrict__ b_hh,
                        const float* __restrict__ h, float* __restrict__ hnew_out,
                        short* __restrict__ hnewb)
{
  const int gid = blockIdx.x*256 + threadIdx.x;
  const int b = gid >> 10, j = gid & 1023;
  float xr = gx[b*3072 + j]        + b_ih[j];
  float xz = gx[b*3072 + 1024 + j] + b_ih[1024+j];
  float xn = gx[b*3072 + 2048 + j] + b_ih[2048+j];
  float hr = gh[b*3072 + j]        + b_hh[j];
  float hz = gh[b*3072 + 1024 + j] + b_hh[1024+j];
  float hn = gh[b*3072 + 2048 + j] + b_hh[2048+j];
  float r = 1.f/(1.f + __expf(-(xr+hr)));
  float z = 1.f/(1.f + __expf(-(xz+hz)));
  float n = tanhf(xn + r*hn);
  float hv = (1.f - z)*n + z*h[b*Hh + j];
  hnew_out[gid] = hv;
  hnewb[gid] = f2bf(hv);
}

extern "C" void kernel_launch(void* const* d_in, const int* in_sizes, int n_in,
                              void* d_out, int out_size, void* d_ws, size_t ws_size,
                              hipStream_t stream)
{
  const int*   dec   = (const int*)  d_in[0];
  const float* h     = (const float*)d_in[1];
  const float* enc   = (const float*)d_in[2];
  const float* emb   = (const float*)d_in[3];
  const float* W_ah  = (const float*)d_in[4];
  const float* b_ah  = (const float*)d_in[5];
  const float* W_ae  = (const float*)d_in[6];
  const float* b_ae  = (const float*)d_in[7];
  const float* wsc   = (const float*)d_in[8];
  const float* W_ih  = (const float*)d_in[9];
  const float* W_hh  = (const float*)d_in[10];
  const float* b_ih  = (const float*)d_in[11];
  const float* b_hh  = (const float*)d_in[12];
  const float* W_out = (const float*)d_in[13];
  const float* b_out = (const float*)d_in[14];
  float* out = (float*)d_out;
  float* hnew_out = out + (size_t)Bb*Vv;

  char* w = (char*)d_ws;
  float* scores = (float*)w;  w += (size_t)65536*4;    // zeroed (atomic target)
  float* ahb    = (float*)w;  w += (size_t)131072*4;   // zeroed
  float* ghb    = (float*)w;  w += (size_t)393216*4;   // zeroed
  float* gxb    = (float*)w;  w += (size_t)393216*4;   // zeroed
  size_t zero_bytes = (size_t)(w - (char*)d_ws);
  float* attn   = (float*)w;  w += (size_t)65536*4;
  short* waeb   = (short*)w;  w += (size_t)2097152*2;
  short* xb     = (short*)w;  w += (size_t)128*2560*2;
  short* hb     = (short*)w;  w += (size_t)131072*2;
  short* hnb    = (short*)w;  w += (size_t)131072*2;
  float* ctxp   = (float*)w;  w += (size_t)4*Bb*TWOH*4;
  short* encb   = (short*)w;  w += (size_t)65536*2048*2;
  const bool big = ((size_t)(w - (char*)d_ws) <= ws_size);

  hipMemsetAsync(d_ws, 0, zero_bytes, stream);
  if (big) k_enc2bf<<<65536, 256, 0, stream>>>(enc, encb);   // 134,217,728 elems / (256*8)
  k_prep<<<4096, 256, 0, stream>>>(W_ae, waeb, h, hb, dec, emb, xb);
  k_gemm128<0><<<dim3(32,2), 256, 0, stream>>>(hb, 1024, W_ah, W_hh, ahb, ghb, nullptr, 8);
  if (big)
    k_scores<true><<<2048, 512, 0, stream>>>(enc, encb, waeb, ahb, b_ah, b_ae, wsc, scores);
  else
    k_scores<false><<<2048, 512, 0, stream>>>(enc, nullptr, waeb, ahb, b_ah, b_ae, wsc, scores);
  k_softmax<<<128, 512, 0, stream>>>(scores, attn);
  if (big){
    k_ctx_bf16<<<512, 256, 0, stream>>>(encb, attn, ctxp);
    k_ctxfin<<<1024, 256, 0, stream>>>(ctxp, xb);
  } else {
    k_ctx_f32<<<dim3(8,128), 256, 0, stream>>>(enc, attn, xb);
  }
  k_gemm128<1><<<dim3(24,4), 256, 0, stream>>>(xb, 2560, W_ih, nullptr, gxb, nullptr, nullptr, 10);
  k_gates<<<512, 256, 0, stream>>>(gxb, ghb, b_ih, b_hh, h, hnew_out, hnb);
  k_gemm128<2><<<dim3(393,1), 256, 0, stream>>>(hnb, 1024, W_out, nullptr, out, nullptr, b_out, 16);
}

// Round 6
// 670.608 us; speedup vs baseline: 1.1092x; 1.1092x over previous
//
#include <hip/hip_runtime.h>
#include <hip/hip_bf16.h>

#define DEVI __device__ __forceinline__

typedef short bf16x8 __attribute__((ext_vector_type(8)));
typedef float f32x4  __attribute__((ext_vector_type(4)));

static constexpr int Bb   = 128;
static constexpr int Ss   = 512;
static constexpr int Hh   = 1024;
static constexpr int Ee   = 512;
static constexpr int Vv   = 50257;
static constexpr int TWOH = 2048;

DEVI short f2bf(float f){ __hip_bfloat16 h = __float2bfloat16(f); return *reinterpret_cast<short*>(&h); }
DEVI float bf2f(short s){ __hip_bfloat16 h = *reinterpret_cast<__hip_bfloat16*>(&s); return __bfloat162float(h); }

DEVI bf16x8 pack8(f32x4 a, f32x4 b){
  bf16x8 v;
  v[0]=f2bf(a[0]); v[1]=f2bf(a[1]); v[2]=f2bf(a[2]); v[3]=f2bf(a[3]);
  v[4]=f2bf(b[0]); v[5]=f2bf(b[1]); v[6]=f2bf(b[2]); v[7]=f2bf(b[3]);
  return v;
}

DEVI void gld_lds16(const void* g, void* l){
  __builtin_amdgcn_global_load_lds((const __attribute__((address_space(1))) void*)g,
                                   (__attribute__((address_space(3))) void*)l, 16, 0, 0);
}

DEVI f32x4 mfma16(bf16x8 a, bf16x8 b, f32x4 c){
  return __builtin_amdgcn_mfma_f32_16x16x32_bf16(a, b, c, 0, 0, 0);
}

// ---------------- enc fp32 -> bf16, fully vectorized streaming pass ----------------
__global__ void k_enc2bf(const float* __restrict__ enc, short* __restrict__ encb)
{
  const size_t i = ((size_t)blockIdx.x*256 + threadIdx.x) * 8;
  f32x4 f0 = *(const f32x4*)(enc + i);
  f32x4 f1 = *(const f32x4*)(enc + i + 4);
  *(bf16x8*)(encb + i) = pack8(f0, f1);
}

// ---------------- prep: convert W_ae->bf16, h->bf16, gather emb into x_bf16 ----------------
__global__ void k_prep(const float* __restrict__ wae, short* __restrict__ waeb,
                       const float* __restrict__ h, short* __restrict__ hb,
                       const int* __restrict__ dec_in, const float* __restrict__ emb,
                       short* __restrict__ xb)
{
  const int total_wae = Hh*TWOH;
  const int total_h   = Bb*Hh;
  const int total_emb = Bb*Ee;
  const int total = total_wae + total_h + total_emb;
  for (int i = blockIdx.x*blockDim.x + threadIdx.x; i < total; i += gridDim.x*blockDim.x){
    if (i < total_wae) waeb[i] = f2bf(wae[i]);
    else if (i < total_wae + total_h){ int j = i - total_wae; hb[j] = f2bf(h[j]); }
    else {
      int j = i - total_wae - total_h;
      int b = j >> 9, e = j & 511;
      xb[b*2560 + e] = f2bf(emb[(size_t)dec_in[b]*Ee + e]);
    }
  }
}

// ---------------- scores GEMM, phase-split counted-vmcnt schedule (T3+T4+T5) ------
// 128x256 tile, 8 waves (2M x 4N), BK=64, 3-buffer LDS ring (144KB), prefetch
// distance 2 K-tiles. Per K-tile: 4 phases {8 ds_read_b128 (one C-quadrant) +
// 2 gld_lds (stage kt+2) ; s_barrier ; setprio(1) 8 MFMA setprio(0) ; s_barrier}.
// vmcnt(6) ONLY at the K-tile boundary (kt+1's loads issued a full K-tile ago are
// retired; kt+2's 6 loads stay in flight across the barrier). Drain only at tail.
__launch_bounds__(512)
__global__ void k_scores8(const short* __restrict__ encbf, const short* __restrict__ waeb,
                          const float* __restrict__ ahb, const float* __restrict__ b_ah,
                          const float* __restrict__ b_ae, const float* __restrict__ wsc,
                          float* __restrict__ scores)
{
  __shared__ __align__(16) char LDSB[147456];   // A: 3 x 16KB @0, B: 3 x 32KB @49152
  const int p  = blockIdx.x;
  const int rt = p >> 2, nb = p & 3;
  const int tid = threadIdx.x, wid = tid>>6, lane = tid&63;
  const int wr = wid>>2, wc = wid&3;
  const int srow = lane>>3, l7 = lane&7;
  const int lo = lane&15, hi4 = lane>>4;
  const short* Ab  = encbf + (size_t)rt*128*TWOH;
  const short* Bbp = waeb  + (size_t)nb*256*TWOH;
  const int aswk = (l7 ^ srow)*8;               // pre-swizzled source k-chunk

  f32x4 acc[4][4] = {};

  auto stageA = [&](int s, int kt){
    #pragma unroll
    for (int i=0;i<2;++i){
      int row = i*64 + wid*8 + srow;
      gld_lds16(Ab + (size_t)row*TWOH + kt*64 + aswk,
                LDSB + s*16384 + i*8192 + wid*1024);
    }
  };
  auto stageB = [&](int s, int kt, int half){
    #pragma unroll
    for (int i=0;i<2;++i){
      int j = half*2 + i;
      int row = j*64 + wid*8 + srow;
      gld_lds16(Bbp + (size_t)row*TWOH + kt*64 + aswk,
                LDSB + 49152 + s*32768 + j*8192 + wid*1024);
    }
  };

  // prologue: kt0 -> buf0, kt1 -> buf1 (12 loads); wait for kt0's 6.
  stageA(0,0); stageB(0,0,0); stageB(0,0,1);
  stageA(1,1); stageB(1,1,0); stageB(1,1,1);
  asm volatile("s_waitcnt vmcnt(6)" ::: "memory");
  __builtin_amdgcn_s_barrier();
  __builtin_amdgcn_sched_barrier(0);

  int cur = 0;
  for (int kt = 0; kt < 32; ++kt){
    const int pb = (cur >= 1) ? cur-1 : 2;      // (kt+2)%3: buffer holding kt-1 (reads done)
    #pragma unroll
    for (int q = 0; q < 4; ++q){
      const int mq = (q>>1)*2, nq = (q&1)*2;
      bf16x8 af[2][2], bq[2][2];
      #pragma unroll
      for (int kk=0;kk<2;++kk){
        const int sw = (kk*64 + hi4*16) ^ (l7<<4);
        #pragma unroll
        for (int i=0;i<2;++i)
          af[i][kk] = *(const bf16x8*)(LDSB + cur*16384 + (wr*64+(mq+i)*16+lo)*128 + sw);
        #pragma unroll
        for (int j=0;j<2;++j)
          bq[j][kk] = *(const bf16x8*)(LDSB + 49152 + cur*32768 + (wc*64+(nq+j)*16+lo)*128 + sw);
      }
      if (kt < 30){                              // stage kt+2 into buf pb, 2 loads/phase
        if (q==0)      stageA(pb, kt+2);
        else if (q==1) stageB(pb, kt+2, 0);
        else if (q==2) stageB(pb, kt+2, 1);
      }
      __builtin_amdgcn_s_barrier();
      __builtin_amdgcn_sched_barrier(0);
      __builtin_amdgcn_s_setprio(1);
      #pragma unroll
      for (int kk=0;kk<2;++kk)
        #pragma unroll
        for (int i=0;i<2;++i)
          #pragma unroll
          for (int j=0;j<2;++j)
            acc[mq+i][nq+j] = mfma16(af[i][kk], bq[j][kk], acc[mq+i][nq+j]);
      __builtin_amdgcn_s_setprio(0);
      if (q==3){
        if (kt < 30)       asm volatile("s_waitcnt vmcnt(6)" ::: "memory");
        else if (kt == 30) asm volatile("s_waitcnt vmcnt(0)" ::: "memory");
      }
      __builtin_amdgcn_s_barrier();
      __builtin_amdgcn_sched_barrier(0);
    }
    cur = (cur==2) ? 0 : cur+1;
  }
  // epilogue: scores[m] += sum_n tanh(ah[b,n]+b_ah+b_ae+ae)*w_score[n]
  const int hi = lane>>4;
  const int b = rt>>2;
  float w4[4], t4[4];
  #pragma unroll
  for (int j=0;j<4;++j){
    int n = nb*256 + wc*64 + j*16 + lo;
    w4[j] = wsc[n];
    t4[j] = ahb[b*Hh + n] + b_ah[n] + b_ae[n];
  }
  #pragma unroll
  for (int i=0;i<4;++i){
    #pragma unroll
    for (int q2=0;q2<4;++q2){
      int m = rt*128 + wr*64 + i*16 + hi*4 + q2;
      float s = 0.f;
      #pragma unroll
      for (int j=0;j<4;++j) s += tanhf(t4[j] + acc[i][j][q2]) * w4[j];
      s += __shfl_xor(s,1); s += __shfl_xor(s,2); s += __shfl_xor(s,4); s += __shfl_xor(s,8);
      if (lo == 0) atomicAdd(&scores[m], s);
    }
  }
}

// ---------------- fallback scores (fp32 enc, 2-phase dbuf) — small-ws path only ----
__launch_bounds__(512)
__global__ void k_scores_f32(const float* __restrict__ enc, const short* __restrict__ waeb,
                             const float* __restrict__ ahb, const float* __restrict__ b_ah,
                             const float* __restrict__ b_ae, const float* __restrict__ wsc,
                             float* __restrict__ scores)
{
  __shared__ __align__(16) short As[2][128*64];
  __shared__ __align__(16) short Bs[2][256*64];
  const int p  = blockIdx.x;
  const int rt = p >> 2, nb = p & 3;
  const int tid = threadIdx.x, wid = tid>>6, lane = tid&63;
  const int wr = wid>>2, wc = wid&3;
  const int srow = lane>>3, l7 = lane&7;
  const int swk = (l7 ^ srow) * 8;
  f32x4 acc[4][4] = {};
  const float* Af  = enc  + (size_t)rt*128*TWOH;
  const short* Bbp = waeb + (size_t)nb*256*TWOH;
  f32x4 pa0[2], pa1[2];

  auto stageB = [&](int s, int kt){
    #pragma unroll
    for (int i=0;i<4;++i){
      int c = wid*4+i, row = c*8+srow;
      gld_lds16(Bbp + (size_t)row*TWOH + kt*64 + swk, (char*)Bs[s] + c*1024);
    }
  };
  auto prefA = [&](int kt){
    #pragma unroll
    for (int i=0;i<2;++i){
      int row = (wid*2+i)*8+srow;
      const float* bp = Af + (size_t)row*TWOH + kt*64 + l7*8;
      pa0[i] = *(const f32x4*)bp; pa1[i] = *(const f32x4*)(bp+4);
    }
  };
  auto commitA = [&](int s){
    #pragma unroll
    for (int i=0;i<2;++i){
      int row = (wid*2+i)*8+srow;
      *(bf16x8*)((char*)As[s] + row*128 + ((l7^srow)<<4)) = pack8(pa0[i], pa1[i]);
    }
  };

  prefA(0); commitA(0); stageB(0,0);
  __syncthreads();
  int cur = 0;
  for (int kt=0; kt<32; ++kt){
    if (kt<31){ prefA(kt+1); stageB(cur^1, kt+1); }
    #pragma unroll
    for (int kk=0;kk<2;++kk){
      bf16x8 af[4], bq[4];
      const int sw = (kk*64 + (lane>>4)*16) ^ (l7<<4);
      #pragma unroll
      for (int i=0;i<4;++i) af[i] = *(const bf16x8*)((const char*)As[cur] + (wr*64+i*16+(lane&15))*128 + sw);
      #pragma unroll
      for (int j=0;j<4;++j) bq[j] = *(const bf16x8*)((const char*)Bs[cur] + (wc*64+j*16+(lane&15))*128 + sw);
      #pragma unroll
      for (int i=0;i<4;++i)
        #pragma unroll
        for (int j=0;j<4;++j)
          acc[i][j] = mfma16(af[i], bq[j], acc[i][j]);
    }
    if (kt<31) commitA(cur^1);
    __syncthreads();
    cur ^= 1;
  }
  const int lo = lane&15, hi = lane>>4;
  const int b = rt>>2;
  float w4[4], t4[4];
  #pragma unroll
  for (int j=0;j<4;++j){
    int n = nb*256 + wc*64 + j*16 + lo;
    w4[j] = wsc[n];
    t4[j] = ahb[b*Hh + n] + b_ah[n] + b_ae[n];
  }
  #pragma unroll
  for (int i=0;i<4;++i){
    #pragma unroll
    for (int q2=0;q2<4;++q2){
      int m = rt*128 + wr*64 + i*16 + hi*4 + q2;
      float s = 0.f;
      #pragma unroll
      for (int j=0;j<4;++j) s += tanhf(t4[j] + acc[i][j][q2]) * w4[j];
      s += __shfl_xor(s,1); s += __shfl_xor(s,2); s += __shfl_xor(s,4); s += __shfl_xor(s,8);
      if (lo == 0) atomicAdd(&scores[m], s);
    }
  }
}

// ---------------- generic 128-row GEMM: A[128,K] bf16 ws, B[N,K] fp32 global --------------
template<int MODE>
__launch_bounds__(256)
__global__ void k_gemm128(const short* __restrict__ A, int lda,
                          const float* __restrict__ B0, const float* __restrict__ B1,
                          float* __restrict__ O0, float* __restrict__ O1,
                          const float* __restrict__ bias, int kiters)
{
  __shared__ __align__(16) short As[2][128*64];
  __shared__ __align__(16) short Bs[2][128*64];
  const int nb = blockIdx.x;
  const int tid = threadIdx.x, wid = tid>>6, lane = tid&63;
  const int wr = wid>>1, wc = wid&1;
  const int srow = lane>>3, l7 = lane&7;
  const int swk = (l7 ^ srow) * 8;

  const float* Bt; int noff; float* Ot; int ostride;
  if constexpr (MODE==0){
    if (nb < 8){ Bt = B0; noff = 0;    Ot = O0; ostride = Hh;   }
    else       { Bt = B1; noff = 1024; Ot = O1; ostride = 3*Hh; }
  } else if constexpr (MODE==1){ Bt = B0; noff = 0; Ot = O0; ostride = 3*Hh; }
  else { Bt = B0; noff = 0; Ot = O0; ostride = Vv; }

  f32x4 acc[4][4] = {};
  f32x4 pb0[4], pb1[4];

  auto stageA = [&](int s, int kt){
    #pragma unroll
    for (int i=0;i<4;++i){
      int c = wid*4+i, row = c*8+srow;
      gld_lds16(A + (size_t)row*lda + kt*64 + swk, (char*)As[s] + c*1024);
    }
  };
  auto prefB = [&](int kt){
    #pragma unroll
    for (int i=0;i<4;++i){
      int row = (wid*4+i)*8+srow;
      int n = nb*128 + row - noff;
      if constexpr (MODE==2) n = (n > Vv-1) ? (Vv-1) : n;
      const float* bp = Bt + (size_t)n*lda + kt*64 + l7*8;
      pb0[i] = *(const f32x4*)bp; pb1[i] = *(const f32x4*)(bp+4);
    }
  };
  auto commitB = [&](int s){
    #pragma unroll
    for (int i=0;i<4;++i){
      int row = (wid*4+i)*8+srow;
      *(bf16x8*)((char*)Bs[s] + row*128 + ((l7^srow)<<4)) = pack8(pb0[i], pb1[i]);
    }
  };

  const int kt0 = blockIdx.y * kiters, kend = kt0 + kiters;
  stageA(0, kt0); prefB(kt0); commitB(0);
  __syncthreads();

  int cur = 0;
  for (int kt = kt0; kt < kend; ++kt){
    if (kt+1 < kend){ stageA(cur^1, kt+1); prefB(kt+1); }
    #pragma unroll
    for (int kk=0;kk<2;++kk){
      bf16x8 af[4], bq[4];
      const int sw = (kk*64 + (lane>>4)*16) ^ (l7<<4);
      #pragma unroll
      for (int i=0;i<4;++i) af[i] = *(const bf16x8*)((const char*)As[cur] + (wr*64+i*16+(lane&15))*128 + sw);
      #pragma unroll
      for (int j=0;j<4;++j) bq[j] = *(const bf16x8*)((const char*)Bs[cur] + (wc*64+j*16+(lane&15))*128 + sw);
      #pragma unroll
      for (int i=0;i<4;++i)
        #pragma unroll
        for (int j=0;j<4;++j)
          acc[i][j] = mfma16(af[i], bq[j], acc[i][j]);
    }
    if (kt+1 < kend) commitB(cur^1);
    __syncthreads();
    cur ^= 1;
  }
  const int lo = lane&15, hi = lane>>4;
  #pragma unroll
  for (int i=0;i<4;++i){
    #pragma unroll
    for (int j=0;j<4;++j){
      int n = nb*128 + wc*64 + j*16 + lo - noff;
      #pragma unroll
      for (int q=0;q<4;++q){
        int m = wr*64 + i*16 + hi*4 + q;
        float v = acc[i][j][q];
        if constexpr (MODE==2){
          if (n < Vv) O0[(size_t)m*Vv + n] = v + bias[n];
        } else {
          atomicAdd(&Ot[(size_t)m*ostride + n], v);
        }
      }
    }
  }
}

// ---------------- softmax over S=512 per batch row ----------------
__global__ void k_softmax(const float* __restrict__ scores, float* __restrict__ attn)
{
  __shared__ float red[512];
  const int b = blockIdx.x, tid = threadIdx.x;
  float v = scores[b*Ss + tid];
  red[tid] = v; __syncthreads();
  for (int off=256; off>0; off>>=1){ if (tid<off) red[tid] = fmaxf(red[tid], red[tid+off]); __syncthreads(); }
  float mx = red[0]; __syncthreads();
  float e = __expf(v - mx);
  red[tid] = e; __syncthreads();
  for (int off=256; off>0; off>>=1){ if (tid<off) red[tid] += red[tid+off]; __syncthreads(); }
  attn[b*Ss + tid] = e / red[0];
}

// ---------------- ctx partial: bf16 enc, 4 row-chunks of 128, vectorized ----------------
__global__ void k_ctx_bf16(const short* __restrict__ encb, const float* __restrict__ attn,
                           float* __restrict__ ctxp)
{
  __shared__ float a[128];
  const int bid = blockIdx.x, b = bid>>2, ch = bid&3, tid = threadIdx.x;
  if (tid < 128) a[tid] = attn[b*Ss + ch*128 + tid];
  __syncthreads();
  const short* e0 = encb + (size_t)(b*Ss + ch*128)*TWOH + tid*8;
  float s[8] = {};
  for (int r=0; r<128; ++r){
    bf16x8 v = *(const bf16x8*)(e0 + (size_t)r*TWOH);
    float w = a[r];
    #pragma unroll
    for (int j=0;j<8;++j) s[j] += w * bf2f(v[j]);
  }
  float* o = ctxp + (size_t)ch*Bb*TWOH + (size_t)b*TWOH + tid*8;
  #pragma unroll
  for (int j=0;j<8;++j) o[j] = s[j];
}

__global__ void k_ctxfin(const float* __restrict__ ctxp, short* __restrict__ xb)
{
  const int g = blockIdx.x*256 + threadIdx.x;
  const int b = g >> 11, col = g & 2047;
  const int N = Bb*TWOH;
  float v = ctxp[g] + ctxp[N+g] + ctxp[2*N+g] + ctxp[3*N+g];
  xb[b*2560 + 512 + col] = f2bf(v);
}

// fallback (small ws): fp32 enc, writes xb directly
__global__ void k_ctx_f32(const float* __restrict__ enc, const float* __restrict__ attn,
                          short* __restrict__ xb)
{
  __shared__ float a[512];
  const int ch = blockIdx.x, b = blockIdx.y, tid = threadIdx.x;
  a[tid]     = attn[b*Ss + tid];
  a[tid+256] = attn[b*Ss + tid + 256];
  __syncthreads();
  const float* e0 = enc + (size_t)b*Ss*TWOH + ch*256 + tid;
  float s0=0.f, s1=0.f, s2=0.f, s3=0.f;
  for (int s=0; s<512; s+=4){
    s0 += a[s]   * e0[(size_t)(s  )*TWOH];
    s1 += a[s+1] * e0[(size_t)(s+1)*TWOH];
    s2 += a[s+2] * e0[(size_t)(s+2)*TWOH];
    s3 += a[s+3] * e0[(size_t)(s+3)*TWOH];
  }
  xb[b*2560 + 512 + ch*256 + tid] = f2bf(s0+s1+s2+s3);
}

// ---------------- GRU gates + h_new ----------------
__global__ void k_gates(const float* __restrict__ gx, const float* __restrict__ gh,
                        const float* __restrict__ b_ih, const float* __restrict__ b_hh,
                        const float* __restrict__ h, float* __restrict__ hnew_out,
                        short* __restrict__ hnewb)
{
  const int gid = blockIdx.x*256 + threadIdx.x;
  const int b = gid >> 10, j = gid & 1023;
  float xr = gx[b*3072 + j]        + b_ih[j];
  float xz = gx[b*3072 + 1024 + j] + b_ih[1024+j];
  float xn = gx[b*3072 + 2048 + j] + b_ih[2048+j];
  float hr = gh[b*3072 + j]        + b_hh[j];
  float hz = gh[b*3072 + 1024 + j] + b_hh[1024+j];
  float hn = gh[b*3072 + 2048 + j] + b_hh[2048+j];
  float r = 1.f/(1.f + __expf(-(xr+hr)));
  float z = 1.f/(1.f + __expf(-(xz+hz)));
  float n = tanhf(xn + r*hn);
  float hv = (1.f - z)*n + z*h[b*Hh + j];
  hnew_out[gid] = hv;
  hnewb[gid] = f2bf(hv);
}

extern "C" void kernel_launch(void* const* d_in, const int* in_sizes, int n_in,
                              void* d_out, int out_size, void* d_ws, size_t ws_size,
                              hipStream_t stream)
{
  const int*   dec   = (const int*)  d_in[0];
  const float* h     = (const float*)d_in[1];
  const float* enc   = (const float*)d_in[2];
  const float* emb   = (const float*)d_in[3];
  const float* W_ah  = (const float*)d_in[4];
  const float* b_ah  = (const float*)d_in[5];
  const float* W_ae  = (const float*)d_in[6];
  const float* b_ae  = (const float*)d_in[7];
  const float* wsc   = (const float*)d_in[8];
  const float* W_ih  = (const float*)d_in[9];
  const float* W_hh  = (const float*)d_in[10];
  const float* b_ih  = (const float*)d_in[11];
  const float* b_hh  = (const float*)d_in[12];
  const float* W_out = (const float*)d_in[13];
  const float* b_out = (const float*)d_in[14];
  float* out = (float*)d_out;
  float* hnew_out = out + (size_t)Bb*Vv;

  char* w = (char*)d_ws;
  float* scores = (float*)w;  w += (size_t)65536*4;    // zeroed (atomic target)
  float* ahb    = (float*)w;  w += (size_t)131072*4;   // zeroed
  float* ghb    = (float*)w;  w += (size_t)393216*4;   // zeroed
  float* gxb    = (float*)w;  w += (size_t)393216*4;   // zeroed
  size_t zero_bytes = (size_t)(w - (char*)d_ws);
  float* attn   = (float*)w;  w += (size_t)65536*4;
  short* waeb   = (short*)w;  w += (size_t)2097152*2;
  short* xb     = (short*)w;  w += (size_t)128*2560*2;
  short* hb     = (short*)w;  w += (size_t)131072*2;
  short* hnb    = (short*)w;  w += (size_t)131072*2;
  float* ctxp   = (float*)w;  w += (size_t)4*Bb*TWOH*4;
  short* encb   = (short*)w;  w += (size_t)65536*2048*2;
  const bool big = ((size_t)(w - (char*)d_ws) <= ws_size);

  hipMemsetAsync(d_ws, 0, zero_bytes, stream);
  if (big) k_enc2bf<<<65536, 256, 0, stream>>>(enc, encb);
  k_prep<<<4096, 256, 0, stream>>>(W_ae, waeb, h, hb, dec, emb, xb);
  k_gemm128<0><<<dim3(32,2), 256, 0, stream>>>(hb, 1024, W_ah, W_hh, ahb, ghb, nullptr, 8);
  if (big)
    k_scores8<<<2048, 512, 0, stream>>>(encb, waeb, ahb, b_ah, b_ae, wsc, scores);
  else
    k_scores_f32<<<2048, 512, 0, stream>>>(enc, waeb, ahb, b_ah, b_ae, wsc, scores);
  k_softmax<<<128, 512, 0, stream>>>(scores, attn);
  if (big){
    k_ctx_bf16<<<512, 256, 0, stream>>>(encb, attn, ctxp);
    k_ctxfin<<<1024, 256, 0, stream>>>(ctxp, xb);
  } else {
    k_ctx_f32<<<dim3(8,128), 256, 0, stream>>>(enc, attn, xb);
  }
  k_gemm128<1><<<dim3(24,4), 256, 0, stream>>>(xb, 2560, W_ih, nullptr, gxb, nullptr, nullptr, 10);
  k_gates<<<512, 256, 0, stream>>>(gxb, ghb, b_ih, b_hh, h, hnew_out, hnb);
  k_gemm128<2><<<dim3(393,1), 256, 0, stream>>>(hnb, 1024, W_out, nullptr, out, nullptr, b_out, 16);
}

// Round 7
// 573.566 us; speedup vs baseline: 1.2969x; 1.1692x over previous
//
#include <hip/hip_runtime.h>
#include <hip/hip_bf16.h>

#define DEVI __device__ __forceinline__

typedef short bf16x8 __attribute__((ext_vector_type(8)));
typedef float f32x4  __attribute__((ext_vector_type(4)));

static constexpr int Bb   = 128;
static constexpr int Ss   = 512;
static constexpr int Hh   = 1024;
static constexpr int Ee   = 512;
static constexpr int Vv   = 50257;
static constexpr int TWOH = 2048;

DEVI short f2bf(float f){ __hip_bfloat16 h = __float2bfloat16(f); return *reinterpret_cast<short*>(&h); }
DEVI float bf2f(short s){ __hip_bfloat16 h = *reinterpret_cast<__hip_bfloat16*>(&s); return __bfloat162float(h); }

DEVI bf16x8 pack8(f32x4 a, f32x4 b){
  bf16x8 v;
  v[0]=f2bf(a[0]); v[1]=f2bf(a[1]); v[2]=f2bf(a[2]); v[3]=f2bf(a[3]);
  v[4]=f2bf(b[0]); v[5]=f2bf(b[1]); v[6]=f2bf(b[2]); v[7]=f2bf(b[3]);
  return v;
}

DEVI void gld_lds16(const void* g, void* l){
  __builtin_amdgcn_global_load_lds((const __attribute__((address_space(1))) void*)g,
                                   (__attribute__((address_space(3))) void*)l, 16, 0, 0);
}

DEVI f32x4 mfma16(bf16x8 a, bf16x8 b, f32x4 c){
  return __builtin_amdgcn_mfma_f32_16x16x32_bf16(a, b, c, 0, 0, 0);
}

// ---------------- enc fp32 -> bf16, fully vectorized streaming pass ----------------
__global__ void k_enc2bf(const float* __restrict__ enc, short* __restrict__ encb)
{
  const size_t i = ((size_t)blockIdx.x*256 + threadIdx.x) * 8;
  f32x4 f0 = *(const f32x4*)(enc + i);
  f32x4 f1 = *(const f32x4*)(enc + i + 4);
  *(bf16x8*)(encb + i) = pack8(f0, f1);
}

// ---------------- prep: convert W_ae->bf16, h->bf16, gather emb into x_bf16 ----------------
__global__ void k_prep(const float* __restrict__ wae, short* __restrict__ waeb,
                       const float* __restrict__ h, short* __restrict__ hb,
                       const int* __restrict__ dec_in, const float* __restrict__ emb,
                       short* __restrict__ xb)
{
  const int total_wae = Hh*TWOH;
  const int total_h   = Bb*Hh;
  const int total_emb = Bb*Ee;
  const int total = total_wae + total_h + total_emb;
  for (int i = blockIdx.x*blockDim.x + threadIdx.x; i < total; i += gridDim.x*blockDim.x){
    if (i < total_wae) waeb[i] = f2bf(wae[i]);
    else if (i < total_wae + total_h){ int j = i - total_wae; hb[j] = f2bf(h[j]); }
    else {
      int j = i - total_wae - total_h;
      int b = j >> 9, e = j & 511;
      xb[b*2560 + e] = f2bf(emb[(size_t)dec_in[b]*Ee + e]);
    }
  }
}

// ---------------- scores GEMM: 256x256 tile, tri-ring A + dbuf B, counted vmcnt ------
// 8 waves (2M x 4N), per-wave 128x64, BK=64. 4 phases/K-tile, 16 MFMA/phase,
// reads 8/4/8/4 b128 (B frags held across the m-half pair -> no re-read).
// LDS 160KB: A 3x32KB ring (distance-2, HBM-streamed encb), B 2x32KB dbuf
// (distance-1, waeb L2-resident: p=rt*4+nb pins one nb per XCD).
// Stage order per tile: B(t+1) at p0,p1; A(t+2) at p2,p3; end-of-tile vmcnt(4)
// retires B(t+1)+A(t+1), keeps A(t+2) in flight across the barrier.
__launch_bounds__(512)
__global__ void k_scores8(const short* __restrict__ encbf, const short* __restrict__ waeb,
                          const float* __restrict__ ahb, const float* __restrict__ b_ah,
                          const float* __restrict__ b_ae, const float* __restrict__ wsc,
                          float* __restrict__ scores)
{
  __shared__ __align__(16) char LDSB[163840];   // A: 3x32KB @0, B: 2x32KB @98304
  const int p  = blockIdx.x;
  const int rt = p >> 2, nb = p & 3;            // rt 0..127, nb 0..3
  const int tid = threadIdx.x, wid = tid>>6, lane = tid&63;
  const int wr = wid>>2, wc = wid&3;            // 2M x 4N waves
  const int srow = lane>>3, l7 = lane&7;
  const int lo = lane&15, hi4 = lane>>4;
  const short* Ab  = encbf + (size_t)rt*256*TWOH;
  const short* Bbp = waeb  + (size_t)nb*256*TWOH;
  const int swk = (l7 ^ srow)*8;                // pre-swizzled source k-chunk

  f32x4 acc[8][4] = {};
  bf16x8 bq[4];

  auto stageA2 = [&](int buf, int kt, int hp){
    #pragma unroll
    for (int i=0;i<2;++i){
      int rnd = hp*2+i;
      int row = rnd*64 + wid*8 + srow;
      gld_lds16(Ab + (size_t)row*TWOH + kt*64 + swk,
                LDSB + buf*32768 + rnd*8192 + wid*1024);
    }
  };
  auto stageB2 = [&](int buf, int kt, int hp){
    #pragma unroll
    for (int i=0;i<2;++i){
      int rnd = hp*2+i;
      int row = rnd*64 + wid*8 + srow;
      gld_lds16(Bbp + (size_t)row*TWOH + kt*64 + swk,
                LDSB + 98304 + buf*32768 + rnd*8192 + wid*1024);
    }
  };
  auto rdA = [&](int buf, int i, int kk)->bf16x8 {
    int row = wr*128 + i*16 + lo;
    int sw = (kk*64 + hi4*16) ^ (l7<<4);
    return *(const bf16x8*)(LDSB + buf*32768 + row*128 + sw);
  };
  auto rdB = [&](int buf, int j, int kk)->bf16x8 {
    int row = wc*64 + j*16 + lo;
    int sw = (kk*64 + hi4*16) ^ (l7<<4);
    return *(const bf16x8*)(LDSB + 98304 + buf*32768 + row*128 + sw);
  };

  // prologue: A(0)->ab0, B(0)->bb0, A(1)->ab1; wait for A0+B0 (A1 stays in flight)
  stageA2(0,0,0); stageA2(0,0,1);
  stageB2(0,0,0); stageB2(0,0,1);
  stageA2(1,1,0); stageA2(1,1,1);
  asm volatile("s_waitcnt vmcnt(4)" ::: "memory");
  __builtin_amdgcn_s_barrier();
  __builtin_amdgcn_sched_barrier(0);

  for (int t = 0; t < 32; ++t){
    const int ab = t%3;
    int ab2 = ab+2; if (ab2>=3) ab2-=3;         // (t+2)%3
    const int bb = t&1;

    // ---- phase 0: kk=0, m 0..3 (A 4 + B 4 reads, 16 MFMA) ----
    if (t<31) stageB2(bb^1, t+1, 0);
    {
      bf16x8 af_[4];
      #pragma unroll
      for (int i=0;i<4;++i) af_[i] = rdA(ab, i, 0);
      #pragma unroll
      for (int j=0;j<4;++j) bq[j] = rdB(bb, j, 0);
      __builtin_amdgcn_s_barrier();
      __builtin_amdgcn_sched_barrier(0);
      __builtin_amdgcn_s_setprio(1);
      #pragma unroll
      for (int i=0;i<4;++i)
        #pragma unroll
        for (int j=0;j<4;++j)
          acc[i][j] = mfma16(af_[i], bq[j], acc[i][j]);
      __builtin_amdgcn_s_setprio(0);
      __builtin_amdgcn_s_barrier();
      __builtin_amdgcn_sched_barrier(0);
    }
    // ---- phase 1: kk=0, m 4..7 (A 4 reads, bq reused, 16 MFMA) ----
    if (t<31) stageB2(bb^1, t+1, 1);
    {
      bf16x8 af_[4];
      #pragma unroll
      for (int i=0;i<4;++i) af_[i] = rdA(ab, 4+i, 0);
      __builtin_amdgcn_s_barrier();
      __builtin_amdgcn_sched_barrier(0);
      __builtin_amdgcn_s_setprio(1);
      #pragma unroll
      for (int i=0;i<4;++i)
        #pragma unroll
        for (int j=0;j<4;++j)
          acc[4+i][j] = mfma16(af_[i], bq[j], acc[4+i][j]);
      __builtin_amdgcn_s_setprio(0);
      __builtin_amdgcn_s_barrier();
      __builtin_amdgcn_sched_barrier(0);
    }
    // ---- phase 2: kk=1, m 0..3 (A 4 + B 4 reads, 16 MFMA) ----
    if (t<30) stageA2(ab2, t+2, 0);
    {
      bf16x8 af_[4];
      #pragma unroll
      for (int i=0;i<4;++i) af_[i] = rdA(ab, i, 1);
      #pragma unroll
      for (int j=0;j<4;++j) bq[j] = rdB(bb, j, 1);
      __builtin_amdgcn_s_barrier();
      __builtin_amdgcn_sched_barrier(0);
      __builtin_amdgcn_s_setprio(1);
      #pragma unroll
      for (int i=0;i<4;++i)
        #pragma unroll
        for (int j=0;j<4;++j)
          acc[i][j] = mfma16(af_[i], bq[j], acc[i][j]);
      __builtin_amdgcn_s_setprio(0);
      __builtin_amdgcn_s_barrier();
      __builtin_amdgcn_sched_barrier(0);
    }
    // ---- phase 3: kk=1, m 4..7 (A 4 reads, 16 MFMA) + end-of-tile wait ----
    if (t<30) stageA2(ab2, t+2, 1);
    {
      bf16x8 af_[4];
      #pragma unroll
      for (int i=0;i<4;++i) af_[i] = rdA(ab, 4+i, 1);
      __builtin_amdgcn_s_barrier();
      __builtin_amdgcn_sched_barrier(0);
      __builtin_amdgcn_s_setprio(1);
      #pragma unroll
      for (int i=0;i<4;++i)
        #pragma unroll
        for (int j=0;j<4;++j)
          acc[4+i][j] = mfma16(af_[i], bq[j], acc[4+i][j]);
      __builtin_amdgcn_s_setprio(0);
      if (t<30)       asm volatile("s_waitcnt vmcnt(4)" ::: "memory");
      else if (t==30) asm volatile("s_waitcnt vmcnt(0)" ::: "memory");
      __builtin_amdgcn_s_barrier();
      __builtin_amdgcn_sched_barrier(0);
    }
  }
  // epilogue: scores[m] += sum_n tanh(ah[b,n]+b_ah+b_ae+ae)*w_score[n]
  const int b = rt >> 1;                        // 256-row tile = half a batch row
  float w4[4], t4[4];
  #pragma unroll
  for (int j=0;j<4;++j){
    int n = nb*256 + wc*64 + j*16 + lo;
    w4[j] = wsc[n];
    t4[j] = ahb[b*Hh + n] + b_ah[n] + b_ae[n];
  }
  #pragma unroll
  for (int i=0;i<8;++i){
    #pragma unroll
    for (int q2=0;q2<4;++q2){
      int m = rt*256 + wr*128 + i*16 + hi4*4 + q2;
      float s = 0.f;
      #pragma unroll
      for (int j=0;j<4;++j) s += tanhf(t4[j] + acc[i][j][q2]) * w4[j];
      s += __shfl_xor(s,1); s += __shfl_xor(s,2); s += __shfl_xor(s,4); s += __shfl_xor(s,8);
      if (lo == 0) atomicAdd(&scores[m], s);
    }
  }
}

// ---------------- fallback scores (fp32 enc, 2-phase dbuf) — small-ws path only ----
__launch_bounds__(512)
__global__ void k_scores_f32(const float* __restrict__ enc, const short* __restrict__ waeb,
                             const float* __restrict__ ahb, const float* __restrict__ b_ah,
                             const float* __restrict__ b_ae, const float* __restrict__ wsc,
                             float* __restrict__ scores)
{
  __shared__ __align__(16) short As[2][128*64];
  __shared__ __align__(16) short Bs[2][256*64];
  const int p  = blockIdx.x;
  const int rt = p >> 2, nb = p & 3;
  const int tid = threadIdx.x, wid = tid>>6, lane = tid&63;
  const int wr = wid>>2, wc = wid&3;
  const int srow = lane>>3, l7 = lane&7;
  const int swk = (l7 ^ srow) * 8;
  f32x4 acc[4][4] = {};
  const float* Af  = enc  + (size_t)rt*128*TWOH;
  const short* Bbp = waeb + (size_t)nb*256*TWOH;
  f32x4 pa0[2], pa1[2];

  auto stageB = [&](int s, int kt){
    #pragma unroll
    for (int i=0;i<4;++i){
      int c = wid*4+i, row = c*8+srow;
      gld_lds16(Bbp + (size_t)row*TWOH + kt*64 + swk, (char*)Bs[s] + c*1024);
    }
  };
  auto prefA = [&](int kt){
    #pragma unroll
    for (int i=0;i<2;++i){
      int row = (wid*2+i)*8+srow;
      const float* bp = Af + (size_t)row*TWOH + kt*64 + l7*8;
      pa0[i] = *(const f32x4*)bp; pa1[i] = *(const f32x4*)(bp+4);
    }
  };
  auto commitA = [&](int s){
    #pragma unroll
    for (int i=0;i<2;++i){
      int row = (wid*2+i)*8+srow;
      *(bf16x8*)((char*)As[s] + row*128 + ((l7^srow)<<4)) = pack8(pa0[i], pa1[i]);
    }
  };

  prefA(0); commitA(0); stageB(0,0);
  __syncthreads();
  int cur = 0;
  for (int kt=0; kt<32; ++kt){
    if (kt<31){ prefA(kt+1); stageB(cur^1, kt+1); }
    #pragma unroll
    for (int kk=0;kk<2;++kk){
      bf16x8 af[4], bq[4];
      const int sw = (kk*64 + (lane>>4)*16) ^ (l7<<4);
      #pragma unroll
      for (int i=0;i<4;++i) af[i] = *(const bf16x8*)((const char*)As[cur] + (wr*64+i*16+(lane&15))*128 + sw);
      #pragma unroll
      for (int j=0;j<4;++j) bq[j] = *(const bf16x8*)((const char*)Bs[cur] + (wc*64+j*16+(lane&15))*128 + sw);
      #pragma unroll
      for (int i=0;i<4;++i)
        #pragma unroll
        for (int j=0;j<4;++j)
          acc[i][j] = mfma16(af[i], bq[j], acc[i][j]);
    }
    if (kt<31) commitA(cur^1);
    __syncthreads();
    cur ^= 1;
  }
  const int lo = lane&15, hi = lane>>4;
  const int b = rt>>2;
  float w4[4], t4[4];
  #pragma unroll
  for (int j=0;j<4;++j){
    int n = nb*256 + wc*64 + j*16 + lo;
    w4[j] = wsc[n];
    t4[j] = ahb[b*Hh + n] + b_ah[n] + b_ae[n];
  }
  #pragma unroll
  for (int i=0;i<4;++i){
    #pragma unroll
    for (int q2=0;q2<4;++q2){
      int m = rt*128 + wr*64 + i*16 + hi*4 + q2;
      float s = 0.f;
      #pragma unroll
      for (int j=0;j<4;++j) s += tanhf(t4[j] + acc[i][j][q2]) * w4[j];
      s += __shfl_xor(s,1); s += __shfl_xor(s,2); s += __shfl_xor(s,4); s += __shfl_xor(s,8);
      if (lo == 0) atomicAdd(&scores[m], s);
    }
  }
}

// ---------------- generic 128-row GEMM: A[128,K] bf16 ws, B[N,K] fp32 global --------------
template<int MODE>
__launch_bounds__(256)
__global__ void k_gemm128(const short* __restrict__ A, int lda,
                          const float* __restrict__ B0, const float* __restrict__ B1,
                          float* __restrict__ O0, float* __restrict__ O1,
                          const float* __restrict__ bias, int kiters)
{
  __shared__ __align__(16) short As[2][128*64];
  __shared__ __align__(16) short Bs[2][128*64];
  const int nb = blockIdx.x;
  const int tid = threadIdx.x, wid = tid>>6, lane = tid&63;
  const int wr = wid>>1, wc = wid&1;
  const int srow = lane>>3, l7 = lane&7;
  const int swk = (l7 ^ srow) * 8;

  const float* Bt; int noff; float* Ot; int ostride;
  if constexpr (MODE==0){
    if (nb < 8){ Bt = B0; noff = 0;    Ot = O0; ostride = Hh;   }
    else       { Bt = B1; noff = 1024; Ot = O1; ostride = 3*Hh; }
  } else if constexpr (MODE==1){ Bt = B0; noff = 0; Ot = O0; ostride = 3*Hh; }
  else { Bt = B0; noff = 0; Ot = O0; ostride = Vv; }

  f32x4 acc[4][4] = {};
  f32x4 pb0[4], pb1[4];

  auto stageA = [&](int s, int kt){
    #pragma unroll
    for (int i=0;i<4;++i){
      int c = wid*4+i, row = c*8+srow;
      gld_lds16(A + (size_t)row*lda + kt*64 + swk, (char*)As[s] + c*1024);
    }
  };
  auto prefB = [&](int kt){
    #pragma unroll
    for (int i=0;i<4;++i){
      int row = (wid*4+i)*8+srow;
      int n = nb*128 + row - noff;
      if constexpr (MODE==2) n = (n > Vv-1) ? (Vv-1) : n;
      const float* bp = Bt + (size_t)n*lda + kt*64 + l7*8;
      pb0[i] = *(const f32x4*)bp; pb1[i] = *(const f32x4*)(bp+4);
    }
  };
  auto commitB = [&](int s){
    #pragma unroll
    for (int i=0;i<4;++i){
      int row = (wid*4+i)*8+srow;
      *(bf16x8*)((char*)Bs[s] + row*128 + ((l7^srow)<<4)) = pack8(pb0[i], pb1[i]);
    }
  };

  const int kt0 = blockIdx.y * kiters, kend = kt0 + kiters;
  stageA(0, kt0); prefB(kt0); commitB(0);
  __syncthreads();

  int cur = 0;
  for (int kt = kt0; kt < kend; ++kt){
    if (kt+1 < kend){ stageA(cur^1, kt+1); prefB(kt+1); }
    #pragma unroll
    for (int kk=0;kk<2;++kk){
      bf16x8 af[4], bq[4];
      const int sw = (kk*64 + (lane>>4)*16) ^ (l7<<4);
      #pragma unroll
      for (int i=0;i<4;++i) af[i] = *(const bf16x8*)((const char*)As[cur] + (wr*64+i*16+(lane&15))*128 + sw);
      #pragma unroll
      for (int j=0;j<4;++j) bq[j] = *(const bf16x8*)((const char*)Bs[cur] + (wc*64+j*16+(lane&15))*128 + sw);
      #pragma unroll
      for (int i=0;i<4;++i)
        #pragma unroll
        for (int j=0;j<4;++j)
          acc[i][j] = mfma16(af[i], bq[j], acc[i][j]);
    }
    if (kt+1 < kend) commitB(cur^1);
    __syncthreads();
    cur ^= 1;
  }
  const int lo = lane&15, hi = lane>>4;
  #pragma unroll
  for (int i=0;i<4;++i){
    #pragma unroll
    for (int j=0;j<4;++j){
      int n = nb*128 + wc*64 + j*16 + lo - noff;
      #pragma unroll
      for (int q=0;q<4;++q){
        int m = wr*64 + i*16 + hi*4 + q;
        float v = acc[i][j][q];
        if constexpr (MODE==2){
          if (n < Vv) O0[(size_t)m*Vv + n] = v + bias[n];
        } else {
          atomicAdd(&Ot[(size_t)m*ostride + n], v);
        }
      }
    }
  }
}

// ---------------- softmax over S=512 per batch row ----------------
__global__ void k_softmax(const float* __restrict__ scores, float* __restrict__ attn)
{
  __shared__ float red[512];
  const int b = blockIdx.x, tid = threadIdx.x;
  float v = scores[b*Ss + tid];
  red[tid] = v; __syncthreads();
  for (int off=256; off>0; off>>=1){ if (tid<off) red[tid] = fmaxf(red[tid], red[tid+off]); __syncthreads(); }
  float mx = red[0]; __syncthreads();
  float e = __expf(v - mx);
  red[tid] = e; __syncthreads();
  for (int off=256; off>0; off>>=1){ if (tid<off) red[tid] += red[tid+off]; __syncthreads(); }
  attn[b*Ss + tid] = e / red[0];
}

// ---------------- ctx partial: bf16 enc, 4 row-chunks of 128, vectorized ----------------
__global__ void k_ctx_bf16(const short* __restrict__ encb, const float* __restrict__ attn,
                           float* __restrict__ ctxp)
{
  __shared__ float a[128];
  const int bid = blockIdx.x, b = bid>>2, ch = bid&3, tid = threadIdx.x;
  if (tid < 128) a[tid] = attn[b*Ss + ch*128 + tid];
  __syncthreads();
  const short* e0 = encb + (size_t)(b*Ss + ch*128)*TWOH + tid*8;
  float s[8] = {};
  for (int r=0; r<128; ++r){
    bf16x8 v = *(const bf16x8*)(e0 + (size_t)r*TWOH);
    float w = a[r];
    #pragma unroll
    for (int j=0;j<8;++j) s[j] += w * bf2f(v[j]);
  }
  float* o = ctxp + (size_t)ch*Bb*TWOH + (size_t)b*TWOH + tid*8;
  #pragma unroll
  for (int j=0;j<8;++j) o[j] = s[j];
}

__global__ void k_ctxfin(const float* __restrict__ ctxp, short* __restrict__ xb)
{
  const int g = blockIdx.x*256 + threadIdx.x;
  const int b = g >> 11, col = g & 2047;
  const int N = Bb*TWOH;
  float v = ctxp[g] + ctxp[N+g] + ctxp[2*N+g] + ctxp[3*N+g];
  xb[b*2560 + 512 + col] = f2bf(v);
}

// fallback (small ws): fp32 enc, writes xb directly
__global__ void k_ctx_f32(const float* __restrict__ enc, const float* __restrict__ attn,
                          short* __restrict__ xb)
{
  __shared__ float a[512];
  const int ch = blockIdx.x, b = blockIdx.y, tid = threadIdx.x;
  a[tid]     = attn[b*Ss + tid];
  a[tid+256] = attn[b*Ss + tid + 256];
  __syncthreads();
  const float* e0 = enc + (size_t)b*Ss*TWOH + ch*256 + tid;
  float s0=0.f, s1=0.f, s2=0.f, s3=0.f;
  for (int s=0; s<512; s+=4){
    s0 += a[s]   * e0[(size_t)(s  )*TWOH];
    s1 += a[s+1] * e0[(size_t)(s+1)*TWOH];
    s2 += a[s+2] * e0[(size_t)(s+2)*TWOH];
    s3 += a[s+3] * e0[(size_t)(s+3)*TWOH];
  }
  xb[b*2560 + 512 + ch*256 + tid] = f2bf(s0+s1+s2+s3);
}

// ---------------- GRU gates + h_new ----------------
__global__ void k_gates(const float* __restrict__ gx, const float* __restrict__ gh,
                        const float* __restrict__ b_ih, const float* __restrict__ b_hh,
                        const float* __restrict__ h, float* __restrict__ hnew_out,
                        short* __restrict__ hnewb)
{
  const int gid = blockIdx.x*256 + threadIdx.x;
  const int b = gid >> 10, j = gid & 1023;
  float xr = gx[b*3072 + j]        + b_ih[j];
  float xz = gx[b*3072 + 1024 + j] + b_ih[1024+j];
  float xn = gx[b*3072 + 2048 + j] + b_ih[2048+j];
  float hr = gh[b*3072 + j]        + b_hh[j];
  float hz = gh[b*3072 + 1024 + j] + b_hh[1024+j];
  float hn = gh[b*3072 + 2048 + j] + b_hh[2048+j];
  float r = 1.f/(1.f + __expf(-(xr+hr)));
  float z = 1.f/(1.f + __expf(-(xz+hz)));
  float n = tanhf(xn + r*hn);
  float hv = (1.f - z)*n + z*h[b*Hh + j];
  hnew_out[gid] = hv;
  hnewb[gid] = f2bf(hv);
}

extern "C" void kernel_launch(void* const* d_in, const int* in_sizes, int n_in,
                              void* d_out, int out_size, void* d_ws, size_t ws_size,
                              hipStream_t stream)
{
  const int*   dec   = (const int*)  d_in[0];
  const float* h     = (const float*)d_in[1];
  const float* enc   = (const float*)d_in[2];
  const float* emb   = (const float*)d_in[3];
  const float* W_ah  = (const float*)d_in[4];
  const float* b_ah  = (const float*)d_in[5];
  const float* W_ae  = (const float*)d_in[6];
  const float* b_ae  = (const float*)d_in[7];
  const float* wsc   = (const float*)d_in[8];
  const float* W_ih  = (const float*)d_in[9];
  const float* W_hh  = (const float*)d_in[10];
  const float* b_ih  = (const float*)d_in[11];
  const float* b_hh  = (const float*)d_in[12];
  const float* W_out = (const float*)d_in[13];
  const float* b_out = (const float*)d_in[14];
  float* out = (float*)d_out;
  float* hnew_out = out + (size_t)Bb*Vv;

  char* w = (char*)d_ws;
  float* scores = (float*)w;  w += (size_t)65536*4;    // zeroed (atomic target)
  float* ahb    = (float*)w;  w += (size_t)131072*4;   // zeroed
  float* ghb    = (float*)w;  w += (size_t)393216*4;   // zeroed
  float* gxb    = (float*)w;  w += (size_t)393216*4;   // zeroed
  size_t zero_bytes = (size_t)(w - (char*)d_ws);
  float* attn   = (float*)w;  w += (size_t)65536*4;
  short* waeb   = (short*)w;  w += (size_t)2097152*2;
  short* xb     = (short*)w;  w += (size_t)128*2560*2;
  short* hb     = (short*)w;  w += (size_t)131072*2;
  short* hnb    = (short*)w;  w += (size_t)131072*2;
  float* ctxp   = (float*)w;  w += (size_t)4*Bb*TWOH*4;
  short* encb   = (short*)w;  w += (size_t)65536*2048*2;
  const bool big = ((size_t)(w - (char*)d_ws) <= ws_size);

  hipMemsetAsync(d_ws, 0, zero_bytes, stream);
  if (big) k_enc2bf<<<65536, 256, 0, stream>>>(enc, encb);
  k_prep<<<4096, 256, 0, stream>>>(W_ae, waeb, h, hb, dec, emb, xb);
  k_gemm128<0><<<dim3(32,2), 256, 0, stream>>>(hb, 1024, W_ah, W_hh, ahb, ghb, nullptr, 8);
  if (big)
    k_scores8<<<1024, 512, 0, stream>>>(encb, waeb, ahb, b_ah, b_ae, wsc, scores);
  else
    k_scores_f32<<<2048, 512, 0, stream>>>(enc, waeb, ahb, b_ah, b_ae, wsc, scores);
  k_softmax<<<128, 512, 0, stream>>>(scores, attn);
  if (big){
    k_ctx_bf16<<<512, 256, 0, stream>>>(encb, attn, ctxp);
    k_ctxfin<<<1024, 256, 0, stream>>>(ctxp, xb);
  } else {
    k_ctx_f32<<<dim3(8,128), 256, 0, stream>>>(enc, attn, xb);
  }
  k_gemm128<1><<<dim3(24,4), 256, 0, stream>>>(xb, 2560, W_ih, nullptr, gxb, nullptr, nullptr, 10);
  k_gates<<<512, 256, 0, stream>>>(gxb, ghb, b_ih, b_hh, h, hnew_out, hnb);
  k_gemm128<2><<<dim3(393,1), 256, 0, stream>>>(hnb, 1024, W_out, nullptr, out, nullptr, b_out, 16);
}

// Round 8
// 548.878 us; speedup vs baseline: 1.3552x; 1.0450x over previous
//
#include <hip/hip_runtime.h>
#include <hip/hip_bf16.h>

#define DEVI __device__ __forceinline__

typedef short bf16x8 __attribute__((ext_vector_type(8)));
typedef float f32x4  __attribute__((ext_vector_type(4)));

static constexpr int Bb   = 128;
static constexpr int Ss   = 512;
static constexpr int Hh   = 1024;
static constexpr int Ee   = 512;
static constexpr int Vv   = 50257;
static constexpr int TWOH = 2048;

DEVI short f2bf(float f){ __hip_bfloat16 h = __float2bfloat16(f); return *reinterpret_cast<short*>(&h); }
DEVI float bf2f(short s){ __hip_bfloat16 h = *reinterpret_cast<__hip_bfloat16*>(&s); return __bfloat162float(h); }

DEVI float tanh_fast(float x){            // 1 - 2/(e^2x + 1): ±inf-safe, ~1e-7 rel err
  float e = __expf(2.0f*x);
  return 1.0f - 2.0f/(e + 1.0f);
}

DEVI bf16x8 pack8(f32x4 a, f32x4 b){
  bf16x8 v;
  v[0]=f2bf(a[0]); v[1]=f2bf(a[1]); v[2]=f2bf(a[2]); v[3]=f2bf(a[3]);
  v[4]=f2bf(b[0]); v[5]=f2bf(b[1]); v[6]=f2bf(b[2]); v[7]=f2bf(b[3]);
  return v;
}

DEVI void gld_lds16(const void* g, void* l){
  __builtin_amdgcn_global_load_lds((const __attribute__((address_space(1))) void*)g,
                                   (__attribute__((address_space(3))) void*)l, 16, 0, 0);
}

DEVI f32x4 mfma16(bf16x8 a, bf16x8 b, f32x4 c){
  return __builtin_amdgcn_mfma_f32_16x16x32_bf16(a, b, c, 0, 0, 0);
}

// ---------------- enc fp32 -> bf16, fully vectorized streaming pass ----------------
__global__ void k_enc2bf(const float* __restrict__ enc, short* __restrict__ encb)
{
  const size_t i = ((size_t)blockIdx.x*256 + threadIdx.x) * 8;
  f32x4 f0 = *(const f32x4*)(enc + i);
  f32x4 f1 = *(const f32x4*)(enc + i + 4);
  *(bf16x8*)(encb + i) = pack8(f0, f1);
}

// ---------------- prep: convert W_ae->bf16, h->bf16, gather emb into x_bf16 ----------------
__global__ void k_prep(const float* __restrict__ wae, short* __restrict__ waeb,
                       const float* __restrict__ h, short* __restrict__ hb,
                       const int* __restrict__ dec_in, const float* __restrict__ emb,
                       short* __restrict__ xb)
{
  const int total_wae = Hh*TWOH;
  const int total_h   = Bb*Hh;
  const int total_emb = Bb*Ee;
  const int total = total_wae + total_h + total_emb;
  for (int i = blockIdx.x*blockDim.x + threadIdx.x; i < total; i += gridDim.x*blockDim.x){
    if (i < total_wae) waeb[i] = f2bf(wae[i]);
    else if (i < total_wae + total_h){ int j = i - total_wae; hb[j] = f2bf(h[j]); }
    else {
      int j = i - total_wae - total_h;
      int b = j >> 9, e = j & 511;
      xb[b*2560 + e] = f2bf(emb[(size_t)dec_in[b]*Ee + e]);
    }
  }
}

// ---------------- scores GEMM: 256x256 tile, tri-ring A + dbuf B, counted vmcnt ------
// 8 waves (2M x 4N), per-wave 128x64, BK=64. 4 phases/K-tile, 16 MFMA/phase.
// vs r7: ONE barrier per phase (leading barrier was scheduling-only; correctness
// needs only the tile-boundary vmcnt->barrier chain), all LDS addresses hoisted
// to registers, sched_barrier(0) only at the tile boundary (s_barrier already
// blocks memory reordering; arithmetic CSEs across it), fast-tanh epilogue.
// Stage order per tile: B(t+1)h0, B(t+1)h1, A(t+2)h0, A(t+2)h1; end-of-tile
// vmcnt(4) retires A(t+1)+B(t+1), keeps A(t+2)'s 4 loads in flight.
__launch_bounds__(512)
__global__ void k_scores8(const short* __restrict__ encbf, const short* __restrict__ waeb,
                          const float* __restrict__ ahb, const float* __restrict__ b_ah,
                          const float* __restrict__ b_ae, const float* __restrict__ wsc,
                          float* __restrict__ scores)
{
  __shared__ __align__(16) char LDSB[163840];   // A: 3x32KB @0, B: 2x32KB @98304
  const int p  = blockIdx.x;
  const int rt = p >> 2, nb = p & 3;            // rt 0..127, nb 0..3
  const int tid = threadIdx.x, wid = tid>>6, lane = tid&63;
  const int wr = wid>>2, wc = wid&3;            // 2M x 4N waves
  const int srow = lane>>3, l7 = lane&7;
  const int lo = lane&15, hi4 = lane>>4;
  const int swk = (l7 ^ srow)*8;                // pre-swizzled source k-chunk (elems)

  // hoisted global/LDS bases
  const short* Ag = encbf + (size_t)rt*256*TWOH + (size_t)(wid*8+srow)*TWOH + swk;
  const short* Bg = waeb  + (size_t)nb*256*TWOH + (size_t)(wid*8+srow)*TWOH + swk;
  char* AW = LDSB + wid*1024;                   // + buf*32768 + rnd*8192 (lane scatter implicit)
  char* BW = LDSB + 98304 + wid*1024;
  const char* AR = LDSB + (wr*128 + lo)*128;    // + buf*32768 + i*2048 + sw
  const char* BR = LDSB + 98304 + (wc*64 + lo)*128;
  const int sw0 = (hi4*16) ^ (l7<<4);           // kk=0 swizzled byte offset
  const int sw1 = (64 + hi4*16) ^ (l7<<4);      // kk=1

  f32x4 acc[8][4] = {};

  auto STA = [&](int buf, int kt, int hp){
    #pragma unroll
    for (int i=0;i<2;++i){
      int rnd = hp*2+i;
      gld_lds16(Ag + (size_t)rnd*64*TWOH + kt*64, AW + buf*32768 + rnd*8192);
    }
  };
  auto STB = [&](int buf, int kt, int hp){
    #pragma unroll
    for (int i=0;i<2;++i){
      int rnd = hp*2+i;
      gld_lds16(Bg + (size_t)rnd*64*TWOH + kt*64, BW + buf*32768 + rnd*8192);
    }
  };

  // prologue: A(0), B(0), A(1); wait for A(0)+B(0); A(1) stays in flight
  STA(0,0,0); STA(0,0,1);
  STB(0,0,0); STB(0,0,1);
  STA(1,1,0); STA(1,1,1);
  asm volatile("s_waitcnt vmcnt(4)" ::: "memory");
  __builtin_amdgcn_s_barrier();
  __builtin_amdgcn_sched_barrier(0);

  int ab = 0;                                   // A ring buffer index = t%3
  for (int t = 0; t < 32; ++t){
    int ab2 = ab+2; if (ab2>=3) ab2-=3;         // (t+2)%3
    const int aO = ab*32768, bO = (t&1)*32768;
    bf16x8 af[4], bq[4];

    // ---- phase 0: stage B(t+1)h0 ; A m0-3 kk0 + B kk0 ; 16 MFMA ----
    if (t<31) STB((t+1)&1, t+1, 0);
    #pragma unroll
    for (int i=0;i<4;++i) af[i] = *(const bf16x8*)(AR + aO + i*2048 + sw0);
    #pragma unroll
    for (int j=0;j<4;++j) bq[j] = *(const bf16x8*)(BR + bO + j*2048 + sw0);
    __builtin_amdgcn_s_setprio(1);
    #pragma unroll
    for (int i=0;i<4;++i)
      #pragma unroll
      for (int j=0;j<4;++j)
        acc[i][j] = mfma16(af[i], bq[j], acc[i][j]);
    __builtin_amdgcn_s_setprio(0);
    __builtin_amdgcn_s_barrier();

    // ---- phase 1: stage B(t+1)h1 ; A m4-7 kk0 (bq reused) ; 16 MFMA ----
    if (t<31) STB((t+1)&1, t+1, 1);
    #pragma unroll
    for (int i=0;i<4;++i) af[i] = *(const bf16x8*)(AR + aO + (4+i)*2048 + sw0);
    __builtin_amdgcn_s_setprio(1);
    #pragma unroll
    for (int i=0;i<4;++i)
      #pragma unroll
      for (int j=0;j<4;++j)
        acc[4+i][j] = mfma16(af[i], bq[j], acc[4+i][j]);
    __builtin_amdgcn_s_setprio(0);
    __builtin_amdgcn_s_barrier();

    // ---- phase 2: stage A(t+2)h0 ; A m0-3 kk1 + B kk1 ; 16 MFMA ----
    if (t<30) STA(ab2, t+2, 0);
    #pragma unroll
    for (int i=0;i<4;++i) af[i] = *(const bf16x8*)(AR + aO + i*2048 + sw1);
    #pragma unroll
    for (int j=0;j<4;++j) bq[j] = *(const bf16x8*)(BR + bO + j*2048 + sw1);
    __builtin_amdgcn_s_setprio(1);
    #pragma unroll
    for (int i=0;i<4;++i)
      #pragma unroll
      for (int j=0;j<4;++j)
        acc[i][j] = mfma16(af[i], bq[j], acc[i][j]);
    __builtin_amdgcn_s_setprio(0);
    __builtin_amdgcn_s_barrier();

    // ---- phase 3: stage A(t+2)h1 ; A m4-7 kk1 ; 16 MFMA ; tile-boundary sync ----
    if (t<30) STA(ab2, t+2, 1);
    #pragma unroll
    for (int i=0;i<4;++i) af[i] = *(const bf16x8*)(AR + aO + (4+i)*2048 + sw1);
    __builtin_amdgcn_s_setprio(1);
    #pragma unroll
    for (int i=0;i<4;++i)
      #pragma unroll
      for (int j=0;j<4;++j)
        acc[4+i][j] = mfma16(af[i], bq[j], acc[4+i][j]);
    __builtin_amdgcn_s_setprio(0);
    if (t<30)       asm volatile("s_waitcnt vmcnt(4)" ::: "memory");
    else if (t==30) asm volatile("s_waitcnt vmcnt(0)" ::: "memory");
    __builtin_amdgcn_s_barrier();
    __builtin_amdgcn_sched_barrier(0);

    ab = (ab==2) ? 0 : ab+1;
  }
  // epilogue: scores[m] += sum_n tanh(ah[b,n]+b_ah+b_ae+ae)*w_score[n]
  const int b = rt >> 1;                        // 256-row tile = half a batch row
  float w4[4], t4[4];
  #pragma unroll
  for (int j=0;j<4;++j){
    int n = nb*256 + wc*64 + j*16 + lo;
    w4[j] = wsc[n];
    t4[j] = ahb[b*Hh + n] + b_ah[n] + b_ae[n];
  }
  #pragma unroll
  for (int i=0;i<8;++i){
    #pragma unroll
    for (int q2=0;q2<4;++q2){
      int m = rt*256 + wr*128 + i*16 + hi4*4 + q2;
      float s = 0.f;
      #pragma unroll
      for (int j=0;j<4;++j) s += tanh_fast(t4[j] + acc[i][j][q2]) * w4[j];
      s += __shfl_xor(s,1); s += __shfl_xor(s,2); s += __shfl_xor(s,4); s += __shfl_xor(s,8);
      if (lo == 0) atomicAdd(&scores[m], s);
    }
  }
}

// ---------------- fallback scores (fp32 enc, 2-phase dbuf) — small-ws path only ----
__launch_bounds__(512)
__global__ void k_scores_f32(const float* __restrict__ enc, const short* __restrict__ waeb,
                             const float* __restrict__ ahb, const float* __restrict__ b_ah,
                             const float* __restrict__ b_ae, const float* __restrict__ wsc,
                             float* __restrict__ scores)
{
  __shared__ __align__(16) short As[2][128*64];
  __shared__ __align__(16) short Bs[2][256*64];
  const int p  = blockIdx.x;
  const int rt = p >> 2, nb = p & 3;
  const int tid = threadIdx.x, wid = tid>>6, lane = tid&63;
  const int wr = wid>>2, wc = wid&3;
  const int srow = lane>>3, l7 = lane&7;
  const int swk = (l7 ^ srow) * 8;
  f32x4 acc[4][4] = {};
  const float* Af  = enc  + (size_t)rt*128*TWOH;
  const short* Bbp = waeb + (size_t)nb*256*TWOH;
  f32x4 pa0[2], pa1[2];

  auto stageB = [&](int s, int kt){
    #pragma unroll
    for (int i=0;i<4;++i){
      int c = wid*4+i, row = c*8+srow;
      gld_lds16(Bbp + (size_t)row*TWOH + kt*64 + swk, (char*)Bs[s] + c*1024);
    }
  };
  auto prefA = [&](int kt){
    #pragma unroll
    for (int i=0;i<2;++i){
      int row = (wid*2+i)*8+srow;
      const float* bp = Af + (size_t)row*TWOH + kt*64 + l7*8;
      pa0[i] = *(const f32x4*)bp; pa1[i] = *(const f32x4*)(bp+4);
    }
  };
  auto commitA = [&](int s){
    #pragma unroll
    for (int i=0;i<2;++i){
      int row = (wid*2+i)*8+srow;
      *(bf16x8*)((char*)As[s] + row*128 + ((l7^srow)<<4)) = pack8(pa0[i], pa1[i]);
    }
  };

  prefA(0); commitA(0); stageB(0,0);
  __syncthreads();
  int cur = 0;
  for (int kt=0; kt<32; ++kt){
    if (kt<31){ prefA(kt+1); stageB(cur^1, kt+1); }
    #pragma unroll
    for (int kk=0;kk<2;++kk){
      bf16x8 af[4], bq[4];
      const int sw = (kk*64 + (lane>>4)*16) ^ (l7<<4);
      #pragma unroll
      for (int i=0;i<4;++i) af[i] = *(const bf16x8*)((const char*)As[cur] + (wr*64+i*16+(lane&15))*128 + sw);
      #pragma unroll
      for (int j=0;j<4;++j) bq[j] = *(const bf16x8*)((const char*)Bs[cur] + (wc*64+j*16+(lane&15))*128 + sw);
      #pragma unroll
      for (int i=0;i<4;++i)
        #pragma unroll
        for (int j=0;j<4;++j)
          acc[i][j] = mfma16(af[i], bq[j], acc[i][j]);
    }
    if (kt<31) commitA(cur^1);
    __syncthreads();
    cur ^= 1;
  }
  const int lo = lane&15, hi = lane>>4;
  const int b = rt>>2;
  float w4[4], t4[4];
  #pragma unroll
  for (int j=0;j<4;++j){
    int n = nb*256 + wc*64 + j*16 + lo;
    w4[j] = wsc[n];
    t4[j] = ahb[b*Hh + n] + b_ah[n] + b_ae[n];
  }
  #pragma unroll
  for (int i=0;i<4;++i){
    #pragma unroll
    for (int q2=0;q2<4;++q2){
      int m = rt*128 + wr*64 + i*16 + hi*4 + q2;
      float s = 0.f;
      #pragma unroll
      for (int j=0;j<4;++j) s += tanhf(t4[j] + acc[i][j][q2]) * w4[j];
      s += __shfl_xor(s,1); s += __shfl_xor(s,2); s += __shfl_xor(s,4); s += __shfl_xor(s,8);
      if (lo == 0) atomicAdd(&scores[m], s);
    }
  }
}

// ---------------- generic 128-row GEMM: A[128,K] bf16 ws, B[N,K] fp32 global --------------
template<int MODE>
__launch_bounds__(256)
__global__ void k_gemm128(const short* __restrict__ A, int lda,
                          const float* __restrict__ B0, const float* __restrict__ B1,
                          float* __restrict__ O0, float* __restrict__ O1,
                          const float* __restrict__ bias, int kiters)
{
  __shared__ __align__(16) short As[2][128*64];
  __shared__ __align__(16) short Bs[2][128*64];
  const int nb = blockIdx.x;
  const int tid = threadIdx.x, wid = tid>>6, lane = tid&63;
  const int wr = wid>>1, wc = wid&1;
  const int srow = lane>>3, l7 = lane&7;
  const int swk = (l7 ^ srow) * 8;

  const float* Bt; int noff; float* Ot; int ostride;
  if constexpr (MODE==0){
    if (nb < 8){ Bt = B0; noff = 0;    Ot = O0; ostride = Hh;   }
    else       { Bt = B1; noff = 1024; Ot = O1; ostride = 3*Hh; }
  } else if constexpr (MODE==1){ Bt = B0; noff = 0; Ot = O0; ostride = 3*Hh; }
  else { Bt = B0; noff = 0; Ot = O0; ostride = Vv; }

  f32x4 acc[4][4] = {};
  f32x4 pb0[4], pb1[4];

  auto stageA = [&](int s, int kt){
    #pragma unroll
    for (int i=0;i<4;++i){
      int c = wid*4+i, row = c*8+srow;
      gld_lds16(A + (size_t)row*lda + kt*64 + swk, (char*)As[s] + c*1024);
    }
  };
  auto prefB = [&](int kt){
    #pragma unroll
    for (int i=0;i<4;++i){
      int row = (wid*4+i)*8+srow;
      int n = nb*128 + row - noff;
      if constexpr (MODE==2) n = (n > Vv-1) ? (Vv-1) : n;
      const float* bp = Bt + (size_t)n*lda + kt*64 + l7*8;
      pb0[i] = *(const f32x4*)bp; pb1[i] = *(const f32x4*)(bp+4);
    }
  };
  auto commitB = [&](int s){
    #pragma unroll
    for (int i=0;i<4;++i){
      int row = (wid*4+i)*8+srow;
      *(bf16x8*)((char*)Bs[s] + row*128 + ((l7^srow)<<4)) = pack8(pb0[i], pb1[i]);
    }
  };

  const int kt0 = blockIdx.y * kiters, kend = kt0 + kiters;
  stageA(0, kt0); prefB(kt0); commitB(0);
  __syncthreads();

  int cur = 0;
  for (int kt = kt0; kt < kend; ++kt){
    if (kt+1 < kend){ stageA(cur^1, kt+1); prefB(kt+1); }
    #pragma unroll
    for (int kk=0;kk<2;++kk){
      bf16x8 af[4], bq[4];
      const int sw = (kk*64 + (lane>>4)*16) ^ (l7<<4);
      #pragma unroll
      for (int i=0;i<4;++i) af[i] = *(const bf16x8*)((const char*)As[cur] + (wr*64+i*16+(lane&15))*128 + sw);
      #pragma unroll
      for (int j=0;j<4;++j) bq[j] = *(const bf16x8*)((const char*)Bs[cur] + (wc*64+j*16+(lane&15))*128 + sw);
      #pragma unroll
      for (int i=0;i<4;++i)
        #pragma unroll
        for (int j=0;j<4;++j)
          acc[i][j] = mfma16(af[i], bq[j], acc[i][j]);
    }
    if (kt+1 < kend) commitB(cur^1);
    __syncthreads();
    cur ^= 1;
  }
  const int lo = lane&15, hi = lane>>4;
  #pragma unroll
  for (int i=0;i<4;++i){
    #pragma unroll
    for (int j=0;j<4;++j){
      int n = nb*128 + wc*64 + j*16 + lo - noff;
      #pragma unroll
      for (int q=0;q<4;++q){
        int m = wr*64 + i*16 + hi*4 + q;
        float v = acc[i][j][q];
        if constexpr (MODE==2){
          if (n < Vv) O0[(size_t)m*Vv + n] = v + bias[n];
        } else {
          atomicAdd(&Ot[(size_t)m*ostride + n], v);
        }
      }
    }
  }
}

// ---------------- softmax over S=512 per batch row ----------------
__global__ void k_softmax(const float* __restrict__ scores, float* __restrict__ attn)
{
  __shared__ float red[512];
  const int b = blockIdx.x, tid = threadIdx.x;
  float v = scores[b*Ss + tid];
  red[tid] = v; __syncthreads();
  for (int off=256; off>0; off>>=1){ if (tid<off) red[tid] = fmaxf(red[tid], red[tid+off]); __syncthreads(); }
  float mx = red[0]; __syncthreads();
  float e = __expf(v - mx);
  red[tid] = e; __syncthreads();
  for (int off=256; off>0; off>>=1){ if (tid<off) red[tid] += red[tid+off]; __syncthreads(); }
  attn[b*Ss + tid] = e / red[0];
}

// ---------------- ctx partial: bf16 enc, 4 row-chunks of 128, vectorized ----------------
__global__ void k_ctx_bf16(const short* __restrict__ encb, const float* __restrict__ attn,
                           float* __restrict__ ctxp)
{
  __shared__ float a[128];
  const int bid = blockIdx.x, b = bid>>2, ch = bid&3, tid = threadIdx.x;
  if (tid < 128) a[tid] = attn[b*Ss + ch*128 + tid];
  __syncthreads();
  const short* e0 = encb + (size_t)(b*Ss + ch*128)*TWOH + tid*8;
  float s[8] = {};
  for (int r=0; r<128; ++r){
    bf16x8 v = *(const bf16x8*)(e0 + (size_t)r*TWOH);
    float w = a[r];
    #pragma unroll
    for (int j=0;j<8;++j) s[j] += w * bf2f(v[j]);
  }
  float* o = ctxp + (size_t)ch*Bb*TWOH + (size_t)b*TWOH + tid*8;
  #pragma unroll
  for (int j=0;j<8;++j) o[j] = s[j];
}

__global__ void k_ctxfin(const float* __restrict__ ctxp, short* __restrict__ xb)
{
  const int g = blockIdx.x*256 + threadIdx.x;
  const int b = g >> 11, col = g & 2047;
  const int N = Bb*TWOH;
  float v = ctxp[g] + ctxp[N+g] + ctxp[2*N+g] + ctxp[3*N+g];
  xb[b*2560 + 512 + col] = f2bf(v);
}

// fallback (small ws): fp32 enc, writes xb directly
__global__ void k_ctx_f32(const float* __restrict__ enc, const float* __restrict__ attn,
                          short* __restrict__ xb)
{
  __shared__ float a[512];
  const int ch = blockIdx.x, b = blockIdx.y, tid = threadIdx.x;
  a[tid]     = attn[b*Ss + tid];
  a[tid+256] = attn[b*Ss + tid + 256];
  __syncthreads();
  const float* e0 = enc + (size_t)b*Ss*TWOH + ch*256 + tid;
  float s0=0.f, s1=0.f, s2=0.f, s3=0.f;
  for (int s=0; s<512; s+=4){
    s0 += a[s]   * e0[(size_t)(s  )*TWOH];
    s1 += a[s+1] * e0[(size_t)(s+1)*TWOH];
    s2 += a[s+2] * e0[(size_t)(s+2)*TWOH];
    s3 += a[s+3] * e0[(size_t)(s+3)*TWOH];
  }
  xb[b*2560 + 512 + ch*256 + tid] = f2bf(s0+s1+s2+s3);
}

// ---------------- GRU gates + h_new ----------------
__global__ void k_gates(const float* __restrict__ gx, const float* __restrict__ gh,
                        const float* __restrict__ b_ih, const float* __restrict__ b_hh,
                        const float* __restrict__ h, float* __restrict__ hnew_out,
                        short* __restrict__ hnewb)
{
  const int gid = blockIdx.x*256 + threadIdx.x;
  const int b = gid >> 10, j = gid & 1023;
  float xr = gx[b*3072 + j]        + b_ih[j];
  float xz = gx[b*3072 + 1024 + j] + b_ih[1024+j];
  float xn = gx[b*3072 + 2048 + j] + b_ih[2048+j];
  float hr = gh[b*3072 + j]        + b_hh[j];
  float hz = gh[b*3072 + 1024 + j] + b_hh[1024+j];
  float hn = gh[b*3072 + 2048 + j] + b_hh[2048+j];
  float r = 1.f/(1.f + __expf(-(xr+hr)));
  float z = 1.f/(1.f + __expf(-(xz+hz)));
  float n = tanhf(xn + r*hn);
  float hv = (1.f - z)*n + z*h[b*Hh + j];
  hnew_out[gid] = hv;
  hnewb[gid] = f2bf(hv);
}

extern "C" void kernel_launch(void* const* d_in, const int* in_sizes, int n_in,
                              void* d_out, int out_size, void* d_ws, size_t ws_size,
                              hipStream_t stream)
{
  const int*   dec   = (const int*)  d_in[0];
  const float* h     = (const float*)d_in[1];
  const float* enc   = (const float*)d_in[2];
  const float* emb   = (const float*)d_in[3];
  const float* W_ah  = (const float*)d_in[4];
  const float* b_ah  = (const float*)d_in[5];
  const float* W_ae  = (const float*)d_in[6];
  const float* b_ae  = (const float*)d_in[7];
  const float* wsc   = (const float*)d_in[8];
  const float* W_ih  = (const float*)d_in[9];
  const float* W_hh  = (const float*)d_in[10];
  const float* b_ih  = (const float*)d_in[11];
  const float* b_hh  = (const float*)d_in[12];
  const float* W_out = (const float*)d_in[13];
  const float* b_out = (const float*)d_in[14];
  float* out = (float*)d_out;
  float* hnew_out = out + (size_t)Bb*Vv;

  char* w = (char*)d_ws;
  float* scores = (float*)w;  w += (size_t)65536*4;    // zeroed (atomic target)
  float* ahb    = (float*)w;  w += (size_t)131072*4;   // zeroed
  float* ghb    = (float*)w;  w += (size_t)393216*4;   // zeroed
  float* gxb    = (float*)w;  w += (size_t)393216*4;   // zeroed
  size_t zero_bytes = (size_t)(w - (char*)d_ws);
  float* attn   = (float*)w;  w += (size_t)65536*4;
  short* waeb   = (short*)w;  w += (size_t)2097152*2;
  short* xb     = (short*)w;  w += (size_t)128*2560*2;
  short* hb     = (short*)w;  w += (size_t)131072*2;
  short* hnb    = (short*)w;  w += (size_t)131072*2;
  float* ctxp   = (float*)w;  w += (size_t)4*Bb*TWOH*4;
  short* encb   = (short*)w;  w += (size_t)65536*2048*2;
  const bool big = ((size_t)(w - (char*)d_ws) <= ws_size);

  hipMemsetAsync(d_ws, 0, zero_bytes, stream);
  if (big) k_enc2bf<<<65536, 256, 0, stream>>>(enc, encb);
  k_prep<<<4096, 256, 0, stream>>>(W_ae, waeb, h, hb, dec, emb, xb);
  k_gemm128<0><<<dim3(32,2), 256, 0, stream>>>(hb, 1024, W_ah, W_hh, ahb, ghb, nullptr, 8);
  if (big)
    k_scores8<<<1024, 512, 0, stream>>>(encb, waeb, ahb, b_ah, b_ae, wsc, scores);
  else
    k_scores_f32<<<2048, 512, 0, stream>>>(enc, waeb, ahb, b_ah, b_ae, wsc, scores);
  k_softmax<<<128, 512, 0, stream>>>(scores, attn);
  if (big){
    k_ctx_bf16<<<512, 256, 0, stream>>>(encb, attn, ctxp);
    k_ctxfin<<<1024, 256, 0, stream>>>(ctxp, xb);
  } else {
    k_ctx_f32<<<dim3(8,128), 256, 0, stream>>>(enc, attn, xb);
  }
  k_gemm128<1><<<dim3(24,4), 256, 0, stream>>>(xb, 2560, W_ih, nullptr, gxb, nullptr, nullptr, 10);
  k_gates<<<512, 256, 0, stream>>>(gxb, ghb, b_ih, b_hh, h, hnew_out, hnb);
  k_gemm128<2><<<dim3(393,1), 256, 0, stream>>>(hnb, 1024, W_out, nullptr, out, nullptr, b_out, 16);
}

// Round 9
// 547.826 us; speedup vs baseline: 1.3578x; 1.0019x over previous
//
#include <hip/hip_runtime.h>
#include <hip/hip_bf16.h>

#define DEVI __device__ __forceinline__

typedef short bf16x8 __attribute__((ext_vector_type(8)));
typedef float f32x4  __attribute__((ext_vector_type(4)));

static constexpr int Bb   = 128;
static constexpr int Ss   = 512;
static constexpr int Hh   = 1024;
static constexpr int Ee   = 512;
static constexpr int Vv   = 50257;
static constexpr int TWOH = 2048;

DEVI short f2bf(float f){ __hip_bfloat16 h = __float2bfloat16(f); return *reinterpret_cast<short*>(&h); }
DEVI float bf2f(short s){ __hip_bfloat16 h = *reinterpret_cast<__hip_bfloat16*>(&s); return __bfloat162float(h); }

DEVI float tanh_fast(float x){            // 1 - 2/(e^2x + 1): ±inf-safe, ~1e-7 rel err
  float e = __expf(2.0f*x);
  return 1.0f - 2.0f/(e + 1.0f);
}

DEVI bf16x8 pack8(f32x4 a, f32x4 b){
  bf16x8 v;
  v[0]=f2bf(a[0]); v[1]=f2bf(a[1]); v[2]=f2bf(a[2]); v[3]=f2bf(a[3]);
  v[4]=f2bf(b[0]); v[5]=f2bf(b[1]); v[6]=f2bf(b[2]); v[7]=f2bf(b[3]);
  return v;
}

DEVI void gld_lds16(const void* g, void* l){
  __builtin_amdgcn_global_load_lds((const __attribute__((address_space(1))) void*)g,
                                   (__attribute__((address_space(3))) void*)l, 16, 0, 0);
}

DEVI f32x4 mfma16(bf16x8 a, bf16x8 b, f32x4 c){
  return __builtin_amdgcn_mfma_f32_16x16x32_bf16(a, b, c, 0, 0, 0);
}

// ---------------- enc fp32 -> bf16, fully vectorized streaming pass ----------------
__global__ void k_enc2bf(const float* __restrict__ enc, short* __restrict__ encb)
{
  const size_t i = ((size_t)blockIdx.x*256 + threadIdx.x) * 8;
  f32x4 f0 = *(const f32x4*)(enc + i);
  f32x4 f1 = *(const f32x4*)(enc + i + 4);
  *(bf16x8*)(encb + i) = pack8(f0, f1);
}

// ---------------- prep: convert W_ae->bf16, h->bf16, gather emb into x_bf16 ----------------
__global__ void k_prep(const float* __restrict__ wae, short* __restrict__ waeb,
                       const float* __restrict__ h, short* __restrict__ hb,
                       const int* __restrict__ dec_in, const float* __restrict__ emb,
                       short* __restrict__ xb)
{
  const int total_wae = Hh*TWOH;
  const int total_h   = Bb*Hh;
  const int total_emb = Bb*Ee;
  const int total = total_wae + total_h + total_emb;
  for (int i = blockIdx.x*blockDim.x + threadIdx.x; i < total; i += gridDim.x*blockDim.x){
    if (i < total_wae) waeb[i] = f2bf(wae[i]);
    else if (i < total_wae + total_h){ int j = i - total_wae; hb[j] = f2bf(h[j]); }
    else {
      int j = i - total_wae - total_h;
      int b = j >> 9, e = j & 511;
      xb[b*2560 + e] = f2bf(emb[(size_t)dec_in[b]*Ee + e]);
    }
  }
}

// ---------------- scores GEMM: 256x256 tile, tri-ring A + dbuf B, counted vmcnt ------
// 8 waves (2M x 4N), per-wave 128x64, BK=64. vs r8: TWO barriers per K-tile
// (stage-order pinning only needs B(t+1)-stages before the mid-barrier and
// A(t+2)-stages after it; each half exposes 12 ds_reads + 32 MFMAs for the
// compiler's counted-lgkmcnt pipeline), and XCD rt-grouping (xcd=q&7 ->
// the 4 nb-sharers of an A panel run concurrently on ONE XCD's L2).
// Stage order per tile: B(t+1)h0,h1 | mid-barrier | A(t+2)h0,h1; end-of-tile
// vmcnt(4) retires A(t+1)+B(t+1), keeps A(t+2)'s 4 loads in flight.
__launch_bounds__(512)
__global__ void k_scores8(const short* __restrict__ encbf, const short* __restrict__ waeb,
                          const float* __restrict__ ahb, const float* __restrict__ b_ah,
                          const float* __restrict__ b_ae, const float* __restrict__ wsc,
                          float* __restrict__ scores)
{
  __shared__ __align__(16) char LDSB[163840];   // A: 3x32KB @0, B: 2x32KB @98304
  const int q  = blockIdx.x;
  const int xcd = q & 7, sl = q >> 3;
  const int rt = xcd*32 + (sl>>2), nb = sl & 3; // rt 0..255, nb 0..3 (bijective)
  const int tid = threadIdx.x, wid = tid>>6, lane = tid&63;
  const int wr = wid>>2, wc = wid&3;            // 2M x 4N waves
  const int srow = lane>>3, l7 = lane&7;
  const int lo = lane&15, hi4 = lane>>4;
  const int swk = (l7 ^ srow)*8;                // pre-swizzled source k-chunk (elems)

  // hoisted global/LDS bases
  const short* Ag = encbf + (size_t)rt*256*TWOH + (size_t)(wid*8+srow)*TWOH + swk;
  const short* Bg = waeb  + (size_t)nb*256*TWOH + (size_t)(wid*8+srow)*TWOH + swk;
  char* AW = LDSB + wid*1024;                   // + buf*32768 + rnd*8192 (lane scatter implicit)
  char* BW = LDSB + 98304 + wid*1024;
  const char* AR = LDSB + (wr*128 + lo)*128;    // + buf*32768 + i*2048 + sw
  const char* BR = LDSB + 98304 + (wc*64 + lo)*128;
  const int sw0 = (hi4*16) ^ (l7<<4);           // kk=0 swizzled byte offset
  const int sw1 = (64 + hi4*16) ^ (l7<<4);      // kk=1

  f32x4 acc[8][4] = {};

  auto STA = [&](int buf, int kt, int hp){
    #pragma unroll
    for (int i=0;i<2;++i){
      int rnd = hp*2+i;
      gld_lds16(Ag + (size_t)rnd*64*TWOH + kt*64, AW + buf*32768 + rnd*8192);
    }
  };
  auto STB = [&](int buf, int kt, int hp){
    #pragma unroll
    for (int i=0;i<2;++i){
      int rnd = hp*2+i;
      gld_lds16(Bg + (size_t)rnd*64*TWOH + kt*64, BW + buf*32768 + rnd*8192);
    }
  };

  // prologue: A(0), B(0), A(1); wait for A(0)+B(0); A(1) stays in flight
  STA(0,0,0); STA(0,0,1);
  STB(0,0,0); STB(0,0,1);
  STA(1,1,0); STA(1,1,1);
  asm volatile("s_waitcnt vmcnt(4)" ::: "memory");
  __builtin_amdgcn_s_barrier();
  __builtin_amdgcn_sched_barrier(0);

  int ab = 0;                                   // A ring buffer index = t%3
  for (int t = 0; t < 32; ++t){
    int ab2 = ab+2; if (ab2>=3) ab2-=3;         // (t+2)%3
    const int aO = ab*32768, bO = (t&1)*32768;
    bf16x8 af[4], bq[4];

    // ---- half 1 (kk0): stage B(t+1); 12 ds_reads + 32 MFMA, free pipeline ----
    if (t<31){ STB((t+1)&1, t+1, 0); STB((t+1)&1, t+1, 1); }
    #pragma unroll
    for (int j=0;j<4;++j) bq[j] = *(const bf16x8*)(BR + bO + j*2048 + sw0);
    #pragma unroll
    for (int i=0;i<4;++i) af[i] = *(const bf16x8*)(AR + aO + i*2048 + sw0);
    __builtin_amdgcn_s_setprio(1);
    #pragma unroll
    for (int i=0;i<4;++i)
      #pragma unroll
      for (int j=0;j<4;++j)
        acc[i][j] = mfma16(af[i], bq[j], acc[i][j]);
    __builtin_amdgcn_s_setprio(0);
    #pragma unroll
    for (int i=0;i<4;++i) af[i] = *(const bf16x8*)(AR + aO + (4+i)*2048 + sw0);
    __builtin_amdgcn_s_setprio(1);
    #pragma unroll
    for (int i=0;i<4;++i)
      #pragma unroll
      for (int j=0;j<4;++j)
        acc[4+i][j] = mfma16(af[i], bq[j], acc[4+i][j]);
    __builtin_amdgcn_s_setprio(0);
    __builtin_amdgcn_s_barrier();               // pins B(t+1) stages before A(t+2)

    // ---- half 2 (kk1): stage A(t+2); 12 ds_reads + 32 MFMA ----
    if (t<30){ STA(ab2, t+2, 0); STA(ab2, t+2, 1); }
    #pragma unroll
    for (int j=0;j<4;++j) bq[j] = *(const bf16x8*)(BR + bO + j*2048 + sw1);
    #pragma unroll
    for (int i=0;i<4;++i) af[i] = *(const bf16x8*)(AR + aO + i*2048 + sw1);
    __builtin_amdgcn_s_setprio(1);
    #pragma unroll
    for (int i=0;i<4;++i)
      #pragma unroll
      for (int j=0;j<4;++j)
        acc[i][j] = mfma16(af[i], bq[j], acc[i][j]);
    __builtin_amdgcn_s_setprio(0);
    #pragma unroll
    for (int i=0;i<4;++i) af[i] = *(const bf16x8*)(AR + aO + (4+i)*2048 + sw1);
    __builtin_amdgcn_s_setprio(1);
    #pragma unroll
    for (int i=0;i<4;++i)
      #pragma unroll
      for (int j=0;j<4;++j)
        acc[4+i][j] = mfma16(af[i], bq[j], acc[4+i][j]);
    __builtin_amdgcn_s_setprio(0);
    if (t<30)       asm volatile("s_waitcnt vmcnt(4)" ::: "memory");
    else if (t==30) asm volatile("s_waitcnt vmcnt(0)" ::: "memory");
    __builtin_amdgcn_s_barrier();
    __builtin_amdgcn_sched_barrier(0);

    ab = (ab==2) ? 0 : ab+1;
  }
  // epilogue: scores[m] += sum_n tanh(ah[b,n]+b_ah+b_ae+ae)*w_score[n]
  const int b = rt >> 1;                        // 256-row tile = half a batch row
  float w4[4], t4[4];
  #pragma unroll
  for (int j=0;j<4;++j){
    int n = nb*256 + wc*64 + j*16 + lo;
    w4[j] = wsc[n];
    t4[j] = ahb[b*Hh + n] + b_ah[n] + b_ae[n];
  }
  #pragma unroll
  for (int i=0;i<8;++i){
    #pragma unroll
    for (int q2=0;q2<4;++q2){
      int m = rt*256 + wr*128 + i*16 + hi4*4 + q2;
      float s = 0.f;
      #pragma unroll
      for (int j=0;j<4;++j) s += tanh_fast(t4[j] + acc[i][j][q2]) * w4[j];
      s += __shfl_xor(s,1); s += __shfl_xor(s,2); s += __shfl_xor(s,4); s += __shfl_xor(s,8);
      if (lo == 0) atomicAdd(&scores[m], s);
    }
  }
}

// ---------------- fallback scores (fp32 enc, 2-phase dbuf) — small-ws path only ----
__launch_bounds__(512)
__global__ void k_scores_f32(const float* __restrict__ enc, const short* __restrict__ waeb,
                             const float* __restrict__ ahb, const float* __restrict__ b_ah,
                             const float* __restrict__ b_ae, const float* __restrict__ wsc,
                             float* __restrict__ scores)
{
  __shared__ __align__(16) short As[2][128*64];
  __shared__ __align__(16) short Bs[2][256*64];
  const int p  = blockIdx.x;
  const int rt = p >> 2, nb = p & 3;
  const int tid = threadIdx.x, wid = tid>>6, lane = tid&63;
  const int wr = wid>>2, wc = wid&3;
  const int srow = lane>>3, l7 = lane&7;
  const int swk = (l7 ^ srow) * 8;
  f32x4 acc[4][4] = {};
  const float* Af  = enc  + (size_t)rt*128*TWOH;
  const short* Bbp = waeb + (size_t)nb*256*TWOH;
  f32x4 pa0[2], pa1[2];

  auto stageB = [&](int s, int kt){
    #pragma unroll
    for (int i=0;i<4;++i){
      int c = wid*4+i, row = c*8+srow;
      gld_lds16(Bbp + (size_t)row*TWOH + kt*64 + swk, (char*)Bs[s] + c*1024);
    }
  };
  auto prefA = [&](int kt){
    #pragma unroll
    for (int i=0;i<2;++i){
      int row = (wid*2+i)*8+srow;
      const float* bp = Af + (size_t)row*TWOH + kt*64 + l7*8;
      pa0[i] = *(const f32x4*)bp; pa1[i] = *(const f32x4*)(bp+4);
    }
  };
  auto commitA = [&](int s){
    #pragma unroll
    for (int i=0;i<2;++i){
      int row = (wid*2+i)*8+srow;
      *(bf16x8*)((char*)As[s] + row*128 + ((l7^srow)<<4)) = pack8(pa0[i], pa1[i]);
    }
  };

  prefA(0); commitA(0); stageB(0,0);
  __syncthreads();
  int cur = 0;
  for (int kt=0; kt<32; ++kt){
    if (kt<31){ prefA(kt+1); stageB(cur^1, kt+1); }
    #pragma unroll
    for (int kk=0;kk<2;++kk){
      bf16x8 af[4], bq[4];
      const int sw = (kk*64 + (lane>>4)*16) ^ (l7<<4);
      #pragma unroll
      for (int i=0;i<4;++i) af[i] = *(const bf16x8*)((const char*)As[cur] + (wr*64+i*16+(lane&15))*128 + sw);
      #pragma unroll
      for (int j=0;j<4;++j) bq[j] = *(const bf16x8*)((const char*)Bs[cur] + (wc*64+j*16+(lane&15))*128 + sw);
      #pragma unroll
      for (int i=0;i<4;++i)
        #pragma unroll
        for (int j=0;j<4;++j)
          acc[i][j] = mfma16(af[i], bq[j], acc[i][j]);
    }
    if (kt<31) commitA(cur^1);
    __syncthreads();
    cur ^= 1;
  }
  const int lo = lane&15, hi = lane>>4;
  const int b = rt>>2;
  float w4[4], t4[4];
  #pragma unroll
  for (int j=0;j<4;++j){
    int n = nb*256 + wc*64 + j*16 + lo;
    w4[j] = wsc[n];
    t4[j] = ahb[b*Hh + n] + b_ah[n] + b_ae[n];
  }
  #pragma unroll
  for (int i=0;i<4;++i){
    #pragma unroll
    for (int q2=0;q2<4;++q2){
      int m = rt*128 + wr*64 + i*16 + hi*4 + q2;
      float s = 0.f;
      #pragma unroll
      for (int j=0;j<4;++j) s += tanhf(t4[j] + acc[i][j][q2]) * w4[j];
      s += __shfl_xor(s,1); s += __shfl_xor(s,2); s += __shfl_xor(s,4); s += __shfl_xor(s,8);
      if (lo == 0) atomicAdd(&scores[m], s);
    }
  }
}

// ---------------- generic 128-row GEMM: A[128,K] bf16 ws, B[N,K] fp32 global --------------
template<int MODE>
__launch_bounds__(256)
__global__ void k_gemm128(const short* __restrict__ A, int lda,
                          const float* __restrict__ B0, const float* __restrict__ B1,
                          float* __restrict__ O0, float* __restrict__ O1,
                          const float* __restrict__ bias, int kiters)
{
  __shared__ __align__(16) short As[2][128*64];
  __shared__ __align__(16) short Bs[2][128*64];
  const int nb = blockIdx.x;
  const int tid = threadIdx.x, wid = tid>>6, lane = tid&63;
  const int wr = wid>>1, wc = wid&1;
  const int srow = lane>>3, l7 = lane&7;
  const int swk = (l7 ^ srow) * 8;

  const float* Bt; int noff; float* Ot; int ostride;
  if constexpr (MODE==0){
    if (nb < 8){ Bt = B0; noff = 0;    Ot = O0; ostride = Hh;   }
    else       { Bt = B1; noff = 1024; Ot = O1; ostride = 3*Hh; }
  } else if constexpr (MODE==1){ Bt = B0; noff = 0; Ot = O0; ostride = 3*Hh; }
  else { Bt = B0; noff = 0; Ot = O0; ostride = Vv; }

  f32x4 acc[4][4] = {};
  f32x4 pb0[4], pb1[4];

  auto stageA = [&](int s, int kt){
    #pragma unroll
    for (int i=0;i<4;++i){
      int c = wid*4+i, row = c*8+srow;
      gld_lds16(A + (size_t)row*lda + kt*64 + swk, (char*)As[s] + c*1024);
    }
  };
  auto prefB = [&](int kt){
    #pragma unroll
    for (int i=0;i<4;++i){
      int row = (wid*4+i)*8+srow;
      int n = nb*128 + row - noff;
      if constexpr (MODE==2) n = (n > Vv-1) ? (Vv-1) : n;
      const float* bp = Bt + (size_t)n*lda + kt*64 + l7*8;
      pb0[i] = *(const f32x4*)bp; pb1[i] = *(const f32x4*)(bp+4);
    }
  };
  auto commitB = [&](int s){
    #pragma unroll
    for (int i=0;i<4;++i){
      int row = (wid*4+i)*8+srow;
      *(bf16x8*)((char*)Bs[s] + row*128 + ((l7^srow)<<4)) = pack8(pb0[i], pb1[i]);
    }
  };

  const int kt0 = blockIdx.y * kiters, kend = kt0 + kiters;
  stageA(0, kt0); prefB(kt0); commitB(0);
  __syncthreads();

  int cur = 0;
  for (int kt = kt0; kt < kend; ++kt){
    if (kt+1 < kend){ stageA(cur^1, kt+1); prefB(kt+1); }
    #pragma unroll
    for (int kk=0;kk<2;++kk){
      bf16x8 af[4], bq[4];
      const int sw = (kk*64 + (lane>>4)*16) ^ (l7<<4);
      #pragma unroll
      for (int i=0;i<4;++i) af[i] = *(const bf16x8*)((const char*)As[cur] + (wr*64+i*16+(lane&15))*128 + sw);
      #pragma unroll
      for (int j=0;j<4;++j) bq[j] = *(const bf16x8*)((const char*)Bs[cur] + (wc*64+j*16+(lane&15))*128 + sw);
      #pragma unroll
      for (int i=0;i<4;++i)
        #pragma unroll
        for (int j=0;j<4;++j)
          acc[i][j] = mfma16(af[i], bq[j], acc[i][j]);
    }
    if (kt+1 < kend) commitB(cur^1);
    __syncthreads();
    cur ^= 1;
  }
  const int lo = lane&15, hi = lane>>4;
  #pragma unroll
  for (int i=0;i<4;++i){
    #pragma unroll
    for (int j=0;j<4;++j){
      int n = nb*128 + wc*64 + j*16 + lo - noff;
      #pragma unroll
      for (int q=0;q<4;++q){
        int m = wr*64 + i*16 + hi*4 + q;
        float v = acc[i][j][q];
        if constexpr (MODE==2){
          if (n < Vv) O0[(size_t)m*Vv + n] = v + bias[n];
        } else {
          atomicAdd(&Ot[(size_t)m*ostride + n], v);
        }
      }
    }
  }
}

// ---------------- softmax over S=512 per batch row ----------------
__global__ void k_softmax(const float* __restrict__ scores, float* __restrict__ attn)
{
  __shared__ float red[512];
  const int b = blockIdx.x, tid = threadIdx.x;
  float v = scores[b*Ss + tid];
  red[tid] = v; __syncthreads();
  for (int off=256; off>0; off>>=1){ if (tid<off) red[tid] = fmaxf(red[tid], red[tid+off]); __syncthreads(); }
  float mx = red[0]; __syncthreads();
  float e = __expf(v - mx);
  red[tid] = e; __syncthreads();
  for (int off=256; off>0; off>>=1){ if (tid<off) red[tid] += red[tid+off]; __syncthreads(); }
  attn[b*Ss + tid] = e / red[0];
}

// ---------------- ctx partial: bf16 enc, 4 row-chunks of 128, vectorized ----------------
__global__ void k_ctx_bf16(const short* __restrict__ encb, const float* __restrict__ attn,
                           float* __restrict__ ctxp)
{
  __shared__ float a[128];
  const int bid = blockIdx.x, b = bid>>2, ch = bid&3, tid = threadIdx.x;
  if (tid < 128) a[tid] = attn[b*Ss + ch*128 + tid];
  __syncthreads();
  const short* e0 = encb + (size_t)(b*Ss + ch*128)*TWOH + tid*8;
  float s[8] = {};
  for (int r=0; r<128; ++r){
    bf16x8 v = *(const bf16x8*)(e0 + (size_t)r*TWOH);
    float w = a[r];
    #pragma unroll
    for (int j=0;j<8;++j) s[j] += w * bf2f(v[j]);
  }
  float* o = ctxp + (size_t)ch*Bb*TWOH + (size_t)b*TWOH + tid*8;
  #pragma unroll
  for (int j=0;j<8;++j) o[j] = s[j];
}

__global__ void k_ctxfin(const float* __restrict__ ctxp, short* __restrict__ xb)
{
  const int g = blockIdx.x*256 + threadIdx.x;
  const int b = g >> 11, col = g & 2047;
  const int N = Bb*TWOH;
  float v = ctxp[g] + ctxp[N+g] + ctxp[2*N+g] + ctxp[3*N+g];
  xb[b*2560 + 512 + col] = f2bf(v);
}

// fallback (small ws): fp32 enc, writes xb directly
__global__ void k_ctx_f32(const float* __restrict__ enc, const float* __restrict__ attn,
                          short* __restrict__ xb)
{
  __shared__ float a[512];
  const int ch = blockIdx.x, b = blockIdx.y, tid = threadIdx.x;
  a[tid]     = attn[b*Ss + tid];
  a[tid+256] = attn[b*Ss + tid + 256];
  __syncthreads();
  const float* e0 = enc + (size_t)b*Ss*TWOH + ch*256 + tid;
  float s0=0.f, s1=0.f, s2=0.f, s3=0.f;
  for (int s=0; s<512; s+=4){
    s0 += a[s]   * e0[(size_t)(s  )*TWOH];
    s1 += a[s+1] * e0[(size_t)(s+1)*TWOH];
    s2 += a[s+2] * e0[(size_t)(s+2)*TWOH];
    s3 += a[s+3] * e0[(size_t)(s+3)*TWOH];
  }
  xb[b*2560 + 512 + ch*256 + tid] = f2bf(s0+s1+s2+s3);
}

// ---------------- GRU gates + h_new ----------------
__global__ void k_gates(const float* __restrict__ gx, const float* __restrict__ gh,
                        const float* __restrict__ b_ih, const float* __restrict__ b_hh,
                        const float* __restrict__ h, float* __restrict__ hnew_out,
                        short* __restrict__ hnewb)
{
  const int gid = blockIdx.x*256 + threadIdx.x;
  const int b = gid >> 10, j = gid & 1023;
  float xr = gx[b*3072 + j]        + b_ih[j];
  float xz = gx[b*3072 + 1024 + j] + b_ih[1024+j];
  float xn = gx[b*3072 + 2048 + j] + b_ih[2048+j];
  float hr = gh[b*3072 + j]        + b_hh[j];
  float hz = gh[b*3072 + 1024 + j] + b_hh[1024+j];
  float hn = gh[b*3072 + 2048 + j] + b_hh[2048+j];
  float r = 1.f/(1.f + __expf(-(xr+hr)));
  float z = 1.f/(1.f + __expf(-(xz+hz)));
  float n = tanhf(xn + r*hn);
  float hv = (1.f - z)*n + z*h[b*Hh + j];
  hnew_out[gid] = hv;
  hnewb[gid] = f2bf(hv);
}

extern "C" void kernel_launch(void* const* d_in, const int* in_sizes, int n_in,
                              void* d_out, int out_size, void* d_ws, size_t ws_size,
                              hipStream_t stream)
{
  const int*   dec   = (const int*)  d_in[0];
  const float* h     = (const float*)d_in[1];
  const float* enc   = (const float*)d_in[2];
  const float* emb   = (const float*)d_in[3];
  const float* W_ah  = (const float*)d_in[4];
  const float* b_ah  = (const float*)d_in[5];
  const float* W_ae  = (const float*)d_in[6];
  const float* b_ae  = (const float*)d_in[7];
  const float* wsc   = (const float*)d_in[8];
  const float* W_ih  = (const float*)d_in[9];
  const float* W_hh  = (const float*)d_in[10];
  const float* b_ih  = (const float*)d_in[11];
  const float* b_hh  = (const float*)d_in[12];
  const float* W_out = (const float*)d_in[13];
  const float* b_out = (const float*)d_in[14];
  float* out = (float*)d_out;
  float* hnew_out = out + (size_t)Bb*Vv;

  char* w = (char*)d_ws;
  float* scores = (float*)w;  w += (size_t)65536*4;    // zeroed (atomic target)
  float* ahb    = (float*)w;  w += (size_t)131072*4;   // zeroed
  float* ghb    = (float*)w;  w += (size_t)393216*4;   // zeroed
  float* gxb    = (float*)w;  w += (size_t)393216*4;   // zeroed
  size_t zero_bytes = (size_t)(w - (char*)d_ws);
  float* attn   = (float*)w;  w += (size_t)65536*4;
  short* waeb   = (short*)w;  w += (size_t)2097152*2;
  short* xb     = (short*)w;  w += (size_t)128*2560*2;
  short* hb     = (short*)w;  w += (size_t)131072*2;
  short* hnb    = (short*)w;  w += (size_t)131072*2;
  float* ctxp   = (float*)w;  w += (size_t)4*Bb*TWOH*4;
  short* encb   = (short*)w;  w += (size_t)65536*2048*2;
  const bool big = ((size_t)(w - (char*)d_ws) <= ws_size);

  hipMemsetAsync(d_ws, 0, zero_bytes, stream);
  if (big) k_enc2bf<<<65536, 256, 0, stream>>>(enc, encb);
  k_prep<<<4096, 256, 0, stream>>>(W_ae, waeb, h, hb, dec, emb, xb);
  k_gemm128<0><<<dim3(32,2), 256, 0, stream>>>(hb, 1024, W_ah, W_hh, ahb, ghb, nullptr, 8);
  if (big)
    k_scores8<<<1024, 512, 0, stream>>>(encb, waeb, ahb, b_ah, b_ae, wsc, scores);
  else
    k_scores_f32<<<2048, 512, 0, stream>>>(enc, waeb, ahb, b_ah, b_ae, wsc, scores);
  k_softmax<<<128, 512, 0, stream>>>(scores, attn);
  if (big){
    k_ctx_bf16<<<512, 256, 0, stream>>>(encb, attn, ctxp);
    k_ctxfin<<<1024, 256, 0, stream>>>(ctxp, xb);
  } else {
    k_ctx_f32<<<dim3(8,128), 256, 0, stream>>>(enc, attn, xb);
  }
  k_gemm128<1><<<dim3(24,4), 256, 0, stream>>>(xb, 2560, W_ih, nullptr, gxb, nullptr, nullptr, 10);
  k_gates<<<512, 256, 0, stream>>>(gxb, ghb, b_ih, b_hh, h, hnew_out, hnb);
  k_gemm128<2><<<dim3(393,1), 256, 0, stream>>>(hnb, 1024, W_out, nullptr, out, nullptr, b_out, 16);
}